// Round 9
// baseline (343.860 us; speedup 1.0000x reference)
//
#include <hip/hip_runtime.h>
#include <hip/hip_fp16.h>
#include <stdint.h>

// Problem constants
#define BB 2
#define HH 16
#define SS 2048
#define DD 1024
#define DHH 64
// SCALE * log2(e): logits computed directly in log2 domain
#define QSCALE 0.18033688011112042f

typedef _Float16 half8 __attribute__((ext_vector_type(8)));
typedef _Float16 half4 __attribute__((ext_vector_type(4)));
typedef __fp16 fp16x2 __attribute__((ext_vector_type(2)));
typedef float floatx4 __attribute__((ext_vector_type(4)));

__device__ __forceinline__ floatx4 mfma16(half8 a, half8 b, floatx4 c) {
  return __builtin_amdgcn_mfma_f32_16x16x32_f16(a, b, c, 0, 0, 0);
}
__device__ __forceinline__ floatx4 mfma16k16(half4 a, half4 b, floatx4 c) {
  return __builtin_amdgcn_mfma_f32_16x16x16f16(a, b, c, 0, 0, 0);
}

// Async global->LDS DMA, 16B per lane (1KB per wave-issue).
__device__ __forceinline__ void dma16(const _Float16* g, _Float16* l) {
  __builtin_amdgcn_global_load_lds(
      (const __attribute__((address_space(1))) uint32_t*)g,
      (__attribute__((address_space(3))) uint32_t*)l,
      16, 0, 0);
}

// ---------------------------------------------------------------------------
// Kernel 0a: weight conversion (once per call).
// ---------------------------------------------------------------------------
__global__ __launch_bounds__(256) void convert_kernel(
    const float* __restrict__ wq, const float* __restrict__ wk,
    const float* __restrict__ wv, const float* __restrict__ wo,
    _Float16* __restrict__ Wh, _Float16* __restrict__ Wl,
    _Float16* __restrict__ Wot)
{
  __shared__ float St[64][68];
  const int kt = blockIdx.x;
  const int hy = blockIdx.y;
  const int z  = blockIdx.z;
  const int t  = (int)threadIdx.x;
  const int k0 = kt * 64;

  const float* src = (z == 0) ? (wq + hy * (DD * DHH))
                   : (z == 1) ? (wk + hy * (DD * DHH))
                   : (z == 2) ? (wv + hy * (DD * DHH))
                   : wo;

  const int rr = t >> 4, cc = (t & 15) * 4;
  if (z < 3) {
    #pragma unroll
    for (int i = 0; i < 4; ++i)
      *(floatx4*)&St[rr + 16 * i][cc] =
          *(const floatx4*)(src + (k0 + rr + 16 * i) * DHH + cc);
  } else {
    const int d0 = hy * 64;
    #pragma unroll
    for (int i = 0; i < 4; ++i)
      *(floatx4*)&St[rr + 16 * i][cc] =
          *(const floatx4*)(src + (k0 + rr + 16 * i) * 1024 + d0 + cc);
  }
  __syncthreads();

  const int e = t >> 2, kc = (t & 3) * 16;
  if (z < 3) {
    const int n = z * 1024 + hy * 64 + e;
    half8 hi0, hi1, lo0, lo1;
    #pragma unroll
    for (int u = 0; u < 16; ++u) {
      float x = St[kc + u][e];
      _Float16 hh = (_Float16)x;
      _Float16 ll = (_Float16)(x - (float)hh);
      if (u < 8) { hi0[u] = hh; lo0[u] = ll; }
      else       { hi1[u - 8] = hh; lo1[u - 8] = ll; }
    }
    *(half8*)(Wh + n * 1024 + k0 + kc)     = hi0;
    *(half8*)(Wh + n * 1024 + k0 + kc + 8) = hi1;
    *(half8*)(Wl + n * 1024 + k0 + kc)     = lo0;
    *(half8*)(Wl + n * 1024 + k0 + kc + 8) = lo1;
  } else {
    const int d0 = hy * 64;
    half8 hi0, hi1;
    #pragma unroll
    for (int u = 0; u < 16; ++u) {
      _Float16 hh = (_Float16)St[kc + u][e];
      if (u < 8) hi0[u] = hh; else hi1[u - 8] = hh;
    }
    *(half8*)(Wot + (d0 + e) * 1024 + k0 + kc)     = hi0;
    *(half8*)(Wot + (d0 + e) * 1024 + k0 + kc + 8) = hi1;
  }
}

// ---------------------------------------------------------------------------
// Kernel 0b: token split (elementwise, memory-bound).
// ---------------------------------------------------------------------------
__global__ __launch_bounds__(256) void tokens_split_kernel(
    const float* __restrict__ tokens,
    _Float16* __restrict__ th, _Float16* __restrict__ tl)
{
  const int i = ((int)blockIdx.x * 256 + (int)threadIdx.x) * 8;
  floatx4 x0 = *(const floatx4*)(tokens + i);
  floatx4 x1 = *(const floatx4*)(tokens + i + 4);
  half8 h, l;
  #pragma unroll
  for (int j = 0; j < 8; ++j) {
    float x = (j < 4) ? x0[j] : x1[j - 4];
    _Float16 hh = (_Float16)x;
    h[j] = hh;
    l[j] = (_Float16)(x - (float)hh);
  }
  *(half8*)(th + i) = h;
  *(half8*)(tl + i) = l;
}

// ---------------------------------------------------------------------------
// Kernel 1: fused QKV GEMM (unchanged R15: 8-wave, 4-buffer ring,
// counted vmcnt -> s_barrier -> stage(p+3) -> compute(p)).
// ---------------------------------------------------------------------------
__global__ __launch_bounds__(512) void qkv_gemm_kernel(
    const _Float16* __restrict__ th, const _Float16* __restrict__ tl,
    const _Float16* __restrict__ Wh, const _Float16* __restrict__ Wl,
    _Float16* __restrict__ qh, _Float16* __restrict__ ql,
    _Float16* __restrict__ kh, _Float16* __restrict__ kl,
    _Float16* __restrict__ vt)
{
  __shared__ alignas(16) _Float16 sbuf[4][4][128 * 32];   // 128 KB

  const int n0 = blockIdx.x * 128;   // 0..23
  const int m0 = blockIdx.y * 128;   // 0..31
  const int zb = n0 >> 10;           // 0=q, 1=k, 2=v
  const bool is_v = (zb == 2);
  const int t = (int)threadIdx.x;
  const int lane = t & 63, wid = t >> 6;          // wid in [0,8)
  const int l16 = lane & 15, q4 = lane >> 4;
  const int mw = (wid & 3) * 32, nw = (wid >> 2) * 64;

  const int g  = (lane & 7) ^ ((lane >> 3) & 7);
  const int grow  = (lane >> 3) * 2 + (g >> 2);
  const int gcol8 = (g & 3) * 8;
  const int laneoff = (l16 >> 1) * 128 + (((((l16 & 1) << 2) | q4) ^ (l16 >> 1)) * 16);

  const int arr = wid & 3;
  const int rowb = (wid >> 2) * 64;
  const _Float16* src = (arr == 0) ? (th + m0 * 1024)
                      : (arr == 1) ? (Wh + n0 * 1024)
                      : (arr == 2) ? (Wl + n0 * 1024)
                      :              (tl + m0 * 1024);
  const bool stage_active = !(is_v && arr == 3);
  const _Float16* gsrc = src + (rowb + grow) * 1024 + gcol8;

  const floatx4 z4 = {0.0f, 0.0f, 0.0f, 0.0f};
  floatx4 acc[2][4];
  #pragma unroll
  for (int mi = 0; mi < 2; ++mi)
    #pragma unroll
    for (int ni = 0; ni < 4; ++ni) acc[mi][ni] = z4;

  auto stage = [&](int buf, int kt2) {
    if (stage_active) {
      const _Float16* gp = gsrc + kt2 * 32;
      _Float16* dst = &sbuf[buf][arr][rowb * 32];
      #pragma unroll
      for (int j = 0; j < 4; ++j)
        dma16(gp + j * 16 * 1024, dst + j * 16 * 32);
    }
  };

  auto compute = [&](int buf) {
    const char* sAh = (const char*)&sbuf[buf][0][0];
    const char* sBh = (const char*)&sbuf[buf][1][0];
    const char* sBl = (const char*)&sbuf[buf][2][0];
    const char* sAl = (const char*)&sbuf[buf][3][0];
    half8 a_h[2], b_h[4], b_l[4];
    #pragma unroll
    for (int mi = 0; mi < 2; ++mi)
      a_h[mi] = *(const half8*)(sAh + (mw + mi * 16) * 64 + laneoff);
    #pragma unroll
    for (int ni = 0; ni < 4; ++ni) {
      b_h[ni] = *(const half8*)(sBh + (nw + ni * 16) * 64 + laneoff);
      b_l[ni] = *(const half8*)(sBl + (nw + ni * 16) * 64 + laneoff);
    }
    #pragma unroll
    for (int ni = 0; ni < 4; ++ni)
      #pragma unroll
      for (int mi = 0; mi < 2; ++mi)
        acc[mi][ni] = mfma16(a_h[mi], b_h[ni], acc[mi][ni]);
    if (!is_v) {
      half8 a_l[2];
      #pragma unroll
      for (int mi = 0; mi < 2; ++mi)
        a_l[mi] = *(const half8*)(sAl + (mw + mi * 16) * 64 + laneoff);
      #pragma unroll
      for (int ni = 0; ni < 4; ++ni)
        #pragma unroll
        for (int mi = 0; mi < 2; ++mi)
          acc[mi][ni] = mfma16(a_l[mi], b_h[ni], acc[mi][ni]);
    }
    #pragma unroll
    for (int ni = 0; ni < 4; ++ni)
      #pragma unroll
      for (int mi = 0; mi < 2; ++mi)
        acc[mi][ni] = mfma16(a_h[mi], b_l[ni], acc[mi][ni]);
  };

  stage(0, 0);
  stage(1, 1);
  stage(2, 2);

#define QKV_PHASE(P, BUF, VC)                                  \
  asm volatile("s_waitcnt vmcnt(" #VC ")" ::: "memory");       \
  __builtin_amdgcn_s_barrier();                                \
  if ((P) + 3 < 32) stage(((P) + 3) & 3, (P) + 3);             \
  compute(BUF);

  #pragma unroll 1
  for (int p4 = 0; p4 < 28; p4 += 4) {
    QKV_PHASE(p4 + 0, 0, 8)
    QKV_PHASE(p4 + 1, 1, 8)
    QKV_PHASE(p4 + 2, 2, 8)
    QKV_PHASE(p4 + 3, 3, 8)
  }
  QKV_PHASE(28, 0, 8)
  QKV_PHASE(29, 1, 8)
  QKV_PHASE(30, 2, 4)
  QKV_PHASE(31, 3, 0)
#undef QKV_PHASE

  #pragma unroll
  for (int ni = 0; ni < 4; ++ni) {
    const int ncol = n0 + nw + ni * 16;
    const int h = (ncol >> 6) & 15;
    const int e = (ncol & 63) + l16;
    #pragma unroll
    for (int mi = 0; mi < 2; ++mi) {
      #pragma unroll
      for (int r = 0; r < 4; ++r) {
        const int grow2 = m0 + mw + mi * 16 + q4 * 4 + r;
        const int b = grow2 >> 11, s = grow2 & 2047;
        const float v = acc[mi][ni][r];
        const int qkidx = ((b * HH + h) * SS + s) * DHH + e;
        if (zb == 0) {
          const float vs = v * QSCALE;
          const _Float16 hh = (_Float16)vs;
          qh[qkidx] = hh;
          ql[qkidx] = (_Float16)(vs - (float)hh);
        } else if (zb == 1) {
          const _Float16 hh = (_Float16)v;
          kh[qkidx] = hh;
          kl[qkidx] = (_Float16)(v - (float)hh);
        } else {
          // key-permuted V layout within each 64-key block (see attn PV).
          const int sl = s & 63;
          const int sp = (s & ~63) | ((sl & 48) >> 2) | ((sl & 12) << 2) | (sl & 3);
          vt[((b * HH + h) * DHH + e) * SS + sp] = (_Float16)v;
        }
      }
    }
  }
}

// ---------------------------------------------------------------------------
// Kernel 2: flash attention.  R16: LDS-pipe relief.
//  * V fragments go DIRECTLY global->register (prefetched one full
//    iteration ahead, parity double set vfA/vfB — no LDS roundtrip).
//    All 8 waves read identical V lines -> L1 absorbs the redundancy;
//    a wave's 16B/lane load touches 16x64B lines either way (no TA
//    penalty).  Removes 8/24 LDS reads + 1/3 LDS writes per wave-iter
//    and 16 KB LDS (53 -> 37 KB).  LDS pipe was ~80% busy (216 b128
//    instrs + 769 conflict cy per block-iter vs 3.7k budget).
//  * exp2f -> __builtin_amdgcn_exp2f (raw v_exp_f32, no libm fixup).
// ---------------------------------------------------------------------------
__global__ __launch_bounds__(512) void attn_kernel(
    const _Float16* __restrict__ qh, const _Float16* __restrict__ ql,
    const _Float16* __restrict__ kh, const _Float16* __restrict__ kl,
    const _Float16* __restrict__ vt, _Float16* __restrict__ agg)
{
  __shared__ _Float16 Kh[2][64][72], Kl[2][64][72];   // 36 KB

  const int qt = blockIdx.x;
  const int h  = blockIdx.y;
  const int b  = blockIdx.z;
  const int bh = b * HH + h;
  const int t = (int)threadIdx.x;
  const int lane = t & 63, wid = t >> 6;
  const int l16 = lane & 15, q4 = lane >> 4;

  const int sr = t >> 3, sc = (t & 7) * 8;

  half8 qfh[2], qfl[2];
  {
    const int s = qt * 128 + wid * 16 + l16;
    const int base = (bh * SS + s) * DHH + q4 * 8;
    qfh[0] = *(const half8*)(qh + base);
    qfh[1] = *(const half8*)(qh + base + 32);
    qfl[0] = *(const half8*)(ql + base);
    qfl[1] = *(const half8*)(ql + base + 32);
  }

  const floatx4 z4 = {0.0f, 0.0f, 0.0f, 0.0f};
  floatx4 o[4];
  #pragma unroll
  for (int i = 0; i < 4; ++i) o[i] = z4;
  float m_r = -1e30f;
  float l_lane = 0.0f;

  // per-lane V fragment base: row d = sub*16+l16, key chunk q4*16 (permuted)
  const _Float16* vbase = vt + (bh * DHH + l16) * SS + q4 * 16;
  half8 vfA[8], vfB[8];
  auto vload = [&](half8* vf, int k0) {
    #pragma unroll
    for (int sub = 0; sub < 4; ++sub) {
      const _Float16* p = vbase + sub * 16 * SS + k0;
      vf[sub * 2]     = *(const half8*)(p);
      vf[sub * 2 + 1] = *(const half8*)(p + 8);
    }
  };

  half8 pK, pL;
  {
    const int gk = (bh * SS + sr) * DHH + sc;
    pK = *(const half8*)(kh + gk);
    pL = *(const half8*)(kl + gk);
  }
  vload(vfA, 0);
  *(half8*)&Kh[0][sr][sc] = pK;
  *(half8*)&Kl[0][sr][sc] = pL;
  __syncthreads();
  {
    const int gk = (bh * SS + 64 + sr) * DHH + sc;
    pK = *(const half8*)(kh + gk);
    pL = *(const half8*)(kl + gk);
  }
  vload(vfB, 64);

  auto body = [&](int buf, int kt, half8 (&vfc)[8]) {
    // QK^T in log2 domain
    floatx4 sv[4];
    __builtin_amdgcn_s_setprio(1);
    #pragma unroll
    for (int sub = 0; sub < 4; ++sub) {
      const half8 ah0 = *(const half8*)&Kh[buf][sub * 16 + l16][q4 * 8];
      const half8 ah1 = *(const half8*)&Kh[buf][sub * 16 + l16][q4 * 8 + 32];
      const half8 al0 = *(const half8*)&Kl[buf][sub * 16 + l16][q4 * 8];
      const half8 al1 = *(const half8*)&Kl[buf][sub * 16 + l16][q4 * 8 + 32];
      floatx4 s4 = z4;
      s4 = mfma16(ah0, qfh[0], s4);
      s4 = mfma16(ah1, qfh[1], s4);
      s4 = mfma16(al0, qfh[0], s4);
      s4 = mfma16(al1, qfh[1], s4);
      s4 = mfma16(ah0, qfl[0], s4);
      s4 = mfma16(ah1, qfl[1], s4);
      sv[sub] = s4;
    }
    __builtin_amdgcn_s_setprio(0);

    // per-lane max only; cross-lane work deferred to the rare rescale path
    float m0 = fmaxf(fmaxf(sv[0][0], sv[0][1]), fmaxf(sv[0][2], sv[0][3]));
    float m1 = fmaxf(fmaxf(sv[1][0], sv[1][1]), fmaxf(sv[1][2], sv[1][3]));
    float m2 = fmaxf(fmaxf(sv[2][0], sv[2][1]), fmaxf(sv[2][2], sv[2][3]));
    float m3 = fmaxf(fmaxf(sv[3][0], sv[3][1]), fmaxf(sv[3][2], sv[3][3]));
    const float mx = fmaxf(fmaxf(m0, m1), fmaxf(m2, m3));

    if (__any(mx > m_r + 8.0f)) {
      float mc = fmaxf(mx, __shfl_xor(mx, 16));
      mc = fmaxf(mc, __shfl_xor(mc, 32));
      const float mnew = fmaxf(m_r, mc);
      const float alpha = __builtin_amdgcn_exp2f(m_r - mnew);
      m_r = mnew;
      l_lane *= alpha;
      #pragma unroll
      for (int sub = 0; sub < 4; ++sub)
        #pragma unroll
        for (int r = 0; r < 4; ++r) o[sub][r] *= alpha;
    }

    // exp + pack: P chunk c is directly the 16x16x16 B-operand
    half4 p4[4];
    #pragma unroll
    for (int c = 0; c < 4; ++c) {
      const float p0 = __builtin_amdgcn_exp2f(sv[c][0] - m_r);
      const float p1 = __builtin_amdgcn_exp2f(sv[c][1] - m_r);
      const float p2 = __builtin_amdgcn_exp2f(sv[c][2] - m_r);
      const float p3 = __builtin_amdgcn_exp2f(sv[c][3] - m_r);
      l_lane += (p0 + p1) + (p2 + p3);
      const fp16x2 a01 = __builtin_amdgcn_cvt_pkrtz(p0, p1);
      const fp16x2 a23 = __builtin_amdgcn_cvt_pkrtz(p2, p3);
      half4 pv;
      pv[0] = (_Float16)a01[0]; pv[1] = (_Float16)a01[1];
      pv[2] = (_Float16)a23[0]; pv[3] = (_Float16)a23[1];
      p4[c] = pv;
    }

    // stage next K tile (regs) into the other buffer — hidden under PV.
    if (kt < 31) {
      *(half8*)&Kh[buf ^ 1][sr][sc] = pK;
      *(half8*)&Kl[buf ^ 1][sr][sc] = pL;
    }

    // PV from register V fragments: o[sub] covers d = sub*16+(q4*4+r), q=l16
    __builtin_amdgcn_s_setprio(1);
    #pragma unroll
    for (int sub = 0; sub < 4; ++sub) {
      const half8 v01 = vfc[sub * 2];
      const half8 v23 = vfc[sub * 2 + 1];
      const half4 va0 = {v01[0], v01[1], v01[2], v01[3]};
      const half4 va1 = {v01[4], v01[5], v01[6], v01[7]};
      const half4 va2 = {v23[0], v23[1], v23[2], v23[3]};
      const half4 va3 = {v23[4], v23[5], v23[6], v23[7]};
      o[sub] = mfma16k16(va0, p4[0], o[sub]);
      o[sub] = mfma16k16(va1, p4[1], o[sub]);
      o[sub] = mfma16k16(va2, p4[2], o[sub]);
      o[sub] = mfma16k16(va3, p4[3], o[sub]);
    }
    __builtin_amdgcn_s_setprio(0);

    __syncthreads();   // single barrier per iteration

    // prefetch tile kt+2: K into regs (LDS-write next body), V into vfc
    // (consumed at kt+2; WAR on vfc is safe — loads issued after PV reads)
    if (kt < 30) {
      const int k2 = (kt + 2) * 64;
      const int gk = (bh * SS + k2 + sr) * DHH + sc;
      pK = *(const half8*)(kh + gk);
      pL = *(const half8*)(kl + gk);
      vload(vfc, k2);
    }
  };

  #pragma unroll 1
  for (int kt = 0; kt < 32; kt += 2) {
    body(0, kt, vfA);
    body(1, kt + 1, vfB);
  }

  // epilogue: reduce per-lane psum across the q-column's 4 lane groups
  float lsum = l_lane;
  lsum += __shfl_xor(lsum, 16);
  lsum += __shfl_xor(lsum, 32);
  const float inv = 1.0f / lsum;
  const int s = qt * 128 + wid * 16 + l16;
  #pragma unroll
  for (int sub = 0; sub < 4; ++sub) {
    half4 ov;
    #pragma unroll
    for (int r = 0; r < 4; ++r) ov[r] = (_Float16)(o[sub][r] * inv);
    *(half4*)(agg + (b * SS + s) * (HH * DHH) + h * DHH + sub * 16 + q4 * 4) = ov;
  }
}

// ---------------------------------------------------------------------------
// Kernel 3: output projection.  R16: R15-style schedule (8 waves/512
// threads, 4-buffer ring, counted vmcnt -> s_barrier -> stage(p+3) ->
// compute(p); steady vmcnt(4), tail 4/4/2/0).  Was the old drain-at-
// barrier 4-wave kernel at 1 block/CU (~40 us vs ~8 us floor).
// ---------------------------------------------------------------------------
__global__ __launch_bounds__(512) void out_gemm_kernel(
    const _Float16* __restrict__ agg, const _Float16* __restrict__ Wot,
    float* __restrict__ out)
{
  __shared__ alignas(16) _Float16 sbuf[4][2][128 * 32];   // 64 KB
  const int n0 = blockIdx.x * 128;
  const int m0 = blockIdx.y * 128;
  const int t = (int)threadIdx.x;
  const int lane = t & 63, wid = t >> 6;          // wid in [0,8)
  const int l16 = lane & 15, q4 = lane >> 4;
  const int mw = (wid & 3) * 32, nw = (wid >> 2) * 64;

  const int g  = (lane & 7) ^ ((lane >> 3) & 7);
  const int grow  = (lane >> 3) * 2 + (g >> 2);
  const int gcol8 = (g & 3) * 8;
  const int laneoff = (l16 >> 1) * 128 + (((((l16 & 1) << 2) | q4) ^ (l16 >> 1)) * 16);

  // staging: arr = wid&1 (0:A=agg, 1:B=Wot); row quarter = wid>>1
  const int arr = wid & 1;
  const int rowq = (wid >> 1) * 32;
  const _Float16* src = (arr == 0) ? (agg + m0 * 1024) : (Wot + n0 * 1024);
  const _Float16* gsrc = src + (rowq + grow) * 1024 + gcol8;

  const floatx4 z4 = {0.0f, 0.0f, 0.0f, 0.0f};
  floatx4 acc[2][4];
  #pragma unroll
  for (int mi = 0; mi < 2; ++mi)
    #pragma unroll
    for (int ni = 0; ni < 4; ++ni) acc[mi][ni] = z4;

  auto stage = [&](int buf, int kt2) {
    const _Float16* gp = gsrc + kt2 * 32;
    _Float16* dst = &sbuf[buf][arr][rowq * 32];
    #pragma unroll
    for (int j = 0; j < 2; ++j)
      dma16(gp + j * 16 * 1024, dst + j * 16 * 32);
  };

  auto compute = [&](int buf) {
    const char* sA = (const char*)&sbuf[buf][0][0];
    const char* sB = (const char*)&sbuf[buf][1][0];
    half8 a_f[2];
    #pragma unroll
    for (int mi = 0; mi < 2; ++mi)
      a_f[mi] = *(const half8*)(sA + (mw + mi * 16) * 64 + laneoff);
    #pragma unroll
    for (int ni = 0; ni < 4; ++ni) {
      const half8 b_f = *(const half8*)(sB + (nw + ni * 16) * 64 + laneoff);
      #pragma unroll
      for (int mi = 0; mi < 2; ++mi)
        acc[mi][ni] = mfma16(a_f[mi], b_f, acc[mi][ni]);
    }
  };

  stage(0, 0);
  stage(1, 1);
  stage(2, 2);

#define OUT_PHASE(P, BUF, VC)                                  \
  asm volatile("s_waitcnt vmcnt(" #VC ")" ::: "memory");       \
  __builtin_amdgcn_s_barrier();                                \
  if ((P) + 3 < 32) stage(((P) + 3) & 3, (P) + 3);             \
  compute(BUF);

  #pragma unroll 1
  for (int p4 = 0; p4 < 28; p4 += 4) {
    OUT_PHASE(p4 + 0, 0, 4)
    OUT_PHASE(p4 + 1, 1, 4)
    OUT_PHASE(p4 + 2, 2, 4)
    OUT_PHASE(p4 + 3, 3, 4)
  }
  OUT_PHASE(28, 0, 4)
  OUT_PHASE(29, 1, 4)
  OUT_PHASE(30, 2, 2)
  OUT_PHASE(31, 3, 0)
#undef OUT_PHASE

  #pragma unroll
  for (int ni = 0; ni < 4; ++ni)
    #pragma unroll
    for (int mi = 0; mi < 2; ++mi)
      #pragma unroll
      for (int r = 0; r < 4; ++r)
        out[(m0 + mw + mi * 16 + q4 * 4 + r) * 1024 + n0 + nw + ni * 16 + l16] =
            acc[mi][ni][r];
}

// ---------------------------------------------------------------------------
extern "C" void kernel_launch(void* const* d_in, const int* in_sizes, int n_in,
                              void* d_out, int out_size, void* d_ws, size_t ws_size,
                              hipStream_t stream)
{
  const float* tokens = (const float*)d_in[0];
  const float* wq = (const float*)d_in[1];
  const float* wk = (const float*)d_in[2];
  const float* wv = (const float*)d_in[3];
  const float* wo = (const float*)d_in[4];
  float* out = (float*)d_out;

  char* ws = (char*)d_ws;
  // layout (bytes):
  //   qh 0          ql 8388608    kh 16777216   kl 25165824   vt 33554432
  //   Wh 41943040 (6291456)   Wl 48234496 (6291456)   Wot 54525952 (2097152)
  //   th 56623104 (8388608)   tl 65011712 (8388608)      total 73400320
  //   agg aliases th (th dead after qkv_gemm)
  _Float16* qh  = (_Float16*)(ws);
  _Float16* ql  = (_Float16*)(ws + 8388608);
  _Float16* kh  = (_Float16*)(ws + 16777216);
  _Float16* kl  = (_Float16*)(ws + 25165824);
  _Float16* vt  = (_Float16*)(ws + 33554432);
  _Float16* Wh  = (_Float16*)(ws + 41943040);
  _Float16* Wl  = (_Float16*)(ws + 48234496);
  _Float16* Wot = (_Float16*)(ws + 54525952);
  _Float16* th  = (_Float16*)(ws + 56623104);
  _Float16* tl  = (_Float16*)(ws + 65011712);
  _Float16* agg = (_Float16*)(ws + 56623104);

  convert_kernel<<<dim3(16, 16, 4), 256, 0, stream>>>(wq, wk, wv, wo, Wh, Wl, Wot);
  tokens_split_kernel<<<2048, 256, 0, stream>>>(tokens, th, tl);
  qkv_gemm_kernel<<<dim3(24, 32), 512, 0, stream>>>(th, tl, Wh, Wl, qh, ql, kh, kl, vt);
  attn_kernel<<<dim3(16, 16, 2), 512, 0, stream>>>(qh, ql, kh, kl, vt, agg);
  out_gemm_kernel<<<dim3(8, 32), 512, 0, stream>>>(agg, Wot, out);
}

// Round 11
// 267.868 us; speedup vs baseline: 1.2837x; 1.2837x over previous
//
#include <hip/hip_runtime.h>
#include <hip/hip_fp16.h>
#include <stdint.h>

// Problem constants
#define BB 2
#define HH 16
#define SS 2048
#define DD 1024
#define DHH 64
// SCALE * log2(e): logits computed directly in log2 domain
#define QSCALE 0.18033688011112042f

typedef _Float16 half8 __attribute__((ext_vector_type(8)));
typedef _Float16 half4 __attribute__((ext_vector_type(4)));
typedef __fp16 fp16x2 __attribute__((ext_vector_type(2)));
typedef float floatx4 __attribute__((ext_vector_type(4)));

__device__ __forceinline__ floatx4 mfma16(half8 a, half8 b, floatx4 c) {
  return __builtin_amdgcn_mfma_f32_16x16x32_f16(a, b, c, 0, 0, 0);
}
__device__ __forceinline__ floatx4 mfma16k16(half4 a, half4 b, floatx4 c) {
  return __builtin_amdgcn_mfma_f32_16x16x16f16(a, b, c, 0, 0, 0);
}

// Async global->LDS DMA, 16B per lane (1KB per wave-issue).
__device__ __forceinline__ void dma16(const _Float16* g, _Float16* l) {
  __builtin_amdgcn_global_load_lds(
      (const __attribute__((address_space(1))) uint32_t*)g,
      (__attribute__((address_space(3))) uint32_t*)l,
      16, 0, 0);
}

// ---------------------------------------------------------------------------
// Kernel 0a: weight conversion (once per call).
// ---------------------------------------------------------------------------
__global__ __launch_bounds__(256) void convert_kernel(
    const float* __restrict__ wq, const float* __restrict__ wk,
    const float* __restrict__ wv, const float* __restrict__ wo,
    _Float16* __restrict__ Wh, _Float16* __restrict__ Wl,
    _Float16* __restrict__ Wot)
{
  __shared__ float St[64][68];
  const int kt = blockIdx.x;
  const int hy = blockIdx.y;
  const int z  = blockIdx.z;
  const int t  = (int)threadIdx.x;
  const int k0 = kt * 64;

  const float* src = (z == 0) ? (wq + hy * (DD * DHH))
                   : (z == 1) ? (wk + hy * (DD * DHH))
                   : (z == 2) ? (wv + hy * (DD * DHH))
                   : wo;

  const int rr = t >> 4, cc = (t & 15) * 4;
  if (z < 3) {
    #pragma unroll
    for (int i = 0; i < 4; ++i)
      *(floatx4*)&St[rr + 16 * i][cc] =
          *(const floatx4*)(src + (k0 + rr + 16 * i) * DHH + cc);
  } else {
    const int d0 = hy * 64;
    #pragma unroll
    for (int i = 0; i < 4; ++i)
      *(floatx4*)&St[rr + 16 * i][cc] =
          *(const floatx4*)(src + (k0 + rr + 16 * i) * 1024 + d0 + cc);
  }
  __syncthreads();

  const int e = t >> 2, kc = (t & 3) * 16;
  if (z < 3) {
    const int n = z * 1024 + hy * 64 + e;
    half8 hi0, hi1, lo0, lo1;
    #pragma unroll
    for (int u = 0; u < 16; ++u) {
      float x = St[kc + u][e];
      _Float16 hh = (_Float16)x;
      _Float16 ll = (_Float16)(x - (float)hh);
      if (u < 8) { hi0[u] = hh; lo0[u] = ll; }
      else       { hi1[u - 8] = hh; lo1[u - 8] = ll; }
    }
    *(half8*)(Wh + n * 1024 + k0 + kc)     = hi0;
    *(half8*)(Wh + n * 1024 + k0 + kc + 8) = hi1;
    *(half8*)(Wl + n * 1024 + k0 + kc)     = lo0;
    *(half8*)(Wl + n * 1024 + k0 + kc + 8) = lo1;
  } else {
    const int d0 = hy * 64;
    half8 hi0, hi1;
    #pragma unroll
    for (int u = 0; u < 16; ++u) {
      _Float16 hh = (_Float16)St[kc + u][e];
      if (u < 8) hi0[u] = hh; else hi1[u - 8] = hh;
    }
    *(half8*)(Wot + (d0 + e) * 1024 + k0 + kc)     = hi0;
    *(half8*)(Wot + (d0 + e) * 1024 + k0 + kc + 8) = hi1;
  }
}

// ---------------------------------------------------------------------------
// Kernel 0b: token split (elementwise, memory-bound).
// ---------------------------------------------------------------------------
__global__ __launch_bounds__(256) void tokens_split_kernel(
    const float* __restrict__ tokens,
    _Float16* __restrict__ th, _Float16* __restrict__ tl)
{
  const int i = ((int)blockIdx.x * 256 + (int)threadIdx.x) * 8;
  floatx4 x0 = *(const floatx4*)(tokens + i);
  floatx4 x1 = *(const floatx4*)(tokens + i + 4);
  half8 h, l;
  #pragma unroll
  for (int j = 0; j < 8; ++j) {
    float x = (j < 4) ? x0[j] : x1[j - 4];
    _Float16 hh = (_Float16)x;
    h[j] = hh;
    l[j] = (_Float16)(x - (float)hh);
  }
  *(half8*)(th + i) = h;
  *(half8*)(tl + i) = l;
}

// ---------------------------------------------------------------------------
// Kernel 1: fused QKV GEMM (unchanged R15: 8-wave, 4-buffer ring,
// counted vmcnt -> s_barrier -> stage(p+3) -> compute(p)).
// ---------------------------------------------------------------------------
__global__ __launch_bounds__(512) void qkv_gemm_kernel(
    const _Float16* __restrict__ th, const _Float16* __restrict__ tl,
    const _Float16* __restrict__ Wh, const _Float16* __restrict__ Wl,
    _Float16* __restrict__ qh, _Float16* __restrict__ ql,
    _Float16* __restrict__ kh, _Float16* __restrict__ kl,
    _Float16* __restrict__ vt)
{
  __shared__ alignas(16) _Float16 sbuf[4][4][128 * 32];   // 128 KB

  const int n0 = blockIdx.x * 128;   // 0..23
  const int m0 = blockIdx.y * 128;   // 0..31
  const int zb = n0 >> 10;           // 0=q, 1=k, 2=v
  const bool is_v = (zb == 2);
  const int t = (int)threadIdx.x;
  const int lane = t & 63, wid = t >> 6;          // wid in [0,8)
  const int l16 = lane & 15, q4 = lane >> 4;
  const int mw = (wid & 3) * 32, nw = (wid >> 2) * 64;

  const int g  = (lane & 7) ^ ((lane >> 3) & 7);
  const int grow  = (lane >> 3) * 2 + (g >> 2);
  const int gcol8 = (g & 3) * 8;
  const int laneoff = (l16 >> 1) * 128 + (((((l16 & 1) << 2) | q4) ^ (l16 >> 1)) * 16);

  const int arr = wid & 3;
  const int rowb = (wid >> 2) * 64;
  const _Float16* src = (arr == 0) ? (th + m0 * 1024)
                      : (arr == 1) ? (Wh + n0 * 1024)
                      : (arr == 2) ? (Wl + n0 * 1024)
                      :              (tl + m0 * 1024);
  const bool stage_active = !(is_v && arr == 3);
  const _Float16* gsrc = src + (rowb + grow) * 1024 + gcol8;

  const floatx4 z4 = {0.0f, 0.0f, 0.0f, 0.0f};
  floatx4 acc[2][4];
  #pragma unroll
  for (int mi = 0; mi < 2; ++mi)
    #pragma unroll
    for (int ni = 0; ni < 4; ++ni) acc[mi][ni] = z4;

  auto stage = [&](int buf, int kt2) {
    if (stage_active) {
      const _Float16* gp = gsrc + kt2 * 32;
      _Float16* dst = &sbuf[buf][arr][rowb * 32];
      #pragma unroll
      for (int j = 0; j < 4; ++j)
        dma16(gp + j * 16 * 1024, dst + j * 16 * 32);
    }
  };

  auto compute = [&](int buf) {
    const char* sAh = (const char*)&sbuf[buf][0][0];
    const char* sBh = (const char*)&sbuf[buf][1][0];
    const char* sBl = (const char*)&sbuf[buf][2][0];
    const char* sAl = (const char*)&sbuf[buf][3][0];
    half8 a_h[2], b_h[4], b_l[4];
    #pragma unroll
    for (int mi = 0; mi < 2; ++mi)
      a_h[mi] = *(const half8*)(sAh + (mw + mi * 16) * 64 + laneoff);
    #pragma unroll
    for (int ni = 0; ni < 4; ++ni) {
      b_h[ni] = *(const half8*)(sBh + (nw + ni * 16) * 64 + laneoff);
      b_l[ni] = *(const half8*)(sBl + (nw + ni * 16) * 64 + laneoff);
    }
    #pragma unroll
    for (int ni = 0; ni < 4; ++ni)
      #pragma unroll
      for (int mi = 0; mi < 2; ++mi)
        acc[mi][ni] = mfma16(a_h[mi], b_h[ni], acc[mi][ni]);
    if (!is_v) {
      half8 a_l[2];
      #pragma unroll
      for (int mi = 0; mi < 2; ++mi)
        a_l[mi] = *(const half8*)(sAl + (mw + mi * 16) * 64 + laneoff);
      #pragma unroll
      for (int ni = 0; ni < 4; ++ni)
        #pragma unroll
        for (int mi = 0; mi < 2; ++mi)
          acc[mi][ni] = mfma16(a_l[mi], b_h[ni], acc[mi][ni]);
    }
    #pragma unroll
    for (int ni = 0; ni < 4; ++ni)
      #pragma unroll
      for (int mi = 0; mi < 2; ++mi)
        acc[mi][ni] = mfma16(a_h[mi], b_l[ni], acc[mi][ni]);
  };

  stage(0, 0);
  stage(1, 1);
  stage(2, 2);

#define QKV_PHASE(P, BUF, VC)                                  \
  asm volatile("s_waitcnt vmcnt(" #VC ")" ::: "memory");       \
  __builtin_amdgcn_s_barrier();                                \
  if ((P) + 3 < 32) stage(((P) + 3) & 3, (P) + 3);             \
  compute(BUF);

  #pragma unroll 1
  for (int p4 = 0; p4 < 28; p4 += 4) {
    QKV_PHASE(p4 + 0, 0, 8)
    QKV_PHASE(p4 + 1, 1, 8)
    QKV_PHASE(p4 + 2, 2, 8)
    QKV_PHASE(p4 + 3, 3, 8)
  }
  QKV_PHASE(28, 0, 8)
  QKV_PHASE(29, 1, 8)
  QKV_PHASE(30, 2, 4)
  QKV_PHASE(31, 3, 0)
#undef QKV_PHASE

  #pragma unroll
  for (int ni = 0; ni < 4; ++ni) {
    const int ncol = n0 + nw + ni * 16;
    const int h = (ncol >> 6) & 15;
    const int e = (ncol & 63) + l16;
    #pragma unroll
    for (int mi = 0; mi < 2; ++mi) {
      #pragma unroll
      for (int r = 0; r < 4; ++r) {
        const int grow2 = m0 + mw + mi * 16 + q4 * 4 + r;
        const int b = grow2 >> 11, s = grow2 & 2047;
        const float v = acc[mi][ni][r];
        const int qkidx = ((b * HH + h) * SS + s) * DHH + e;
        if (zb == 0) {
          const float vs = v * QSCALE;
          const _Float16 hh = (_Float16)vs;
          qh[qkidx] = hh;
          ql[qkidx] = (_Float16)(vs - (float)hh);
        } else if (zb == 1) {
          const _Float16 hh = (_Float16)v;
          kh[qkidx] = hh;
          kl[qkidx] = (_Float16)(v - (float)hh);
        } else {
          // key-permuted V layout within each 64-key block (see attn PV).
          const int sl = s & 63;
          const int sp = (s & ~63) | ((sl & 48) >> 2) | ((sl & 12) << 2) | (sl & 3);
          vt[((b * HH + h) * DHH + e) * SS + sp] = (_Float16)v;
        }
      }
    }
  }
}

// ---------------------------------------------------------------------------
// Kernel 2: flash attention.  R17 (resubmit after infra timeout): exact
// R11/R15 structure (proven 98.5 us) — V in swizzled LDS, single
// barrier/iter, mid-body stage.  Only retained R16 change: exp2f ->
// __builtin_amdgcn_exp2f (numerics validated in R16, absmax unchanged).
// ---------------------------------------------------------------------------
__global__ __launch_bounds__(512) void attn_kernel(
    const _Float16* __restrict__ qh, const _Float16* __restrict__ ql,
    const _Float16* __restrict__ kh, const _Float16* __restrict__ kl,
    const _Float16* __restrict__ vt, _Float16* __restrict__ agg)
{
  __shared__ _Float16 Kh[2][64][72], Kl[2][64][72];   // 36 KB
  __shared__ _Float16 Vs[2][64][64];                  // 16 KB (swizzled)

  const int qt = blockIdx.x;
  const int h  = blockIdx.y;
  const int b  = blockIdx.z;
  const int bh = b * HH + h;
  const int t = (int)threadIdx.x;
  const int lane = t & 63, wid = t >> 6;
  const int l16 = lane & 15, q4 = lane >> 4;

  const int sr = t >> 3, sc = (t & 7) * 8;
  const int vsw = ((t & 7) ^ (sr & 7)) * 8;           // swizzled V write col

  // swizzled V read chunks (per lane, c2 = 0/1)
  const int vch0 = ((2 * q4 + 0) ^ (l16 & 7)) * 8;
  const int vch1 = ((2 * q4 + 1) ^ (l16 & 7)) * 8;

  half8 qfh[2], qfl[2];
  {
    const int s = qt * 128 + wid * 16 + l16;
    const int base = (bh * SS + s) * DHH + q4 * 8;
    qfh[0] = *(const half8*)(qh + base);
    qfh[1] = *(const half8*)(qh + base + 32);
    qfl[0] = *(const half8*)(ql + base);
    qfl[1] = *(const half8*)(ql + base + 32);
  }

  const floatx4 z4 = {0.0f, 0.0f, 0.0f, 0.0f};
  floatx4 o[4];
  #pragma unroll
  for (int i = 0; i < 4; ++i) o[i] = z4;
  float m_r = -1e30f;
  float l_lane = 0.0f;

  half8 pK, pL, pV;
  // preload tile 0, stage it, then preload tile 1
  {
    const int gk = (bh * SS + sr) * DHH + sc;
    pK = *(const half8*)(kh + gk);
    pL = *(const half8*)(kl + gk);
    pV = *(const half8*)(vt + (bh * DHH + sr) * SS + sc);
  }
  *(half8*)&Kh[0][sr][sc] = pK;
  *(half8*)&Kl[0][sr][sc] = pL;
  *(half8*)&Vs[0][sr][vsw] = pV;
  __syncthreads();
  {
    const int gk = (bh * SS + 64 + sr) * DHH + sc;
    pK = *(const half8*)(kh + gk);
    pL = *(const half8*)(kl + gk);
    pV = *(const half8*)(vt + (bh * DHH + sr) * SS + 64 + sc);
  }

  auto body = [&](int buf, int kt) {
    // QK^T in log2 domain
    floatx4 sv[4];
    __builtin_amdgcn_s_setprio(1);
    #pragma unroll
    for (int sub = 0; sub < 4; ++sub) {
      const half8 ah0 = *(const half8*)&Kh[buf][sub * 16 + l16][q4 * 8];
      const half8 ah1 = *(const half8*)&Kh[buf][sub * 16 + l16][q4 * 8 + 32];
      const half8 al0 = *(const half8*)&Kl[buf][sub * 16 + l16][q4 * 8];
      const half8 al1 = *(const half8*)&Kl[buf][sub * 16 + l16][q4 * 8 + 32];
      floatx4 s4 = z4;
      s4 = mfma16(ah0, qfh[0], s4);
      s4 = mfma16(ah1, qfh[1], s4);
      s4 = mfma16(al0, qfh[0], s4);
      s4 = mfma16(al1, qfh[1], s4);
      s4 = mfma16(ah0, qfl[0], s4);
      s4 = mfma16(ah1, qfl[1], s4);
      sv[sub] = s4;
    }
    __builtin_amdgcn_s_setprio(0);

    // per-lane max only; cross-lane work deferred to the rare rescale path
    float m0 = fmaxf(fmaxf(sv[0][0], sv[0][1]), fmaxf(sv[0][2], sv[0][3]));
    float m1 = fmaxf(fmaxf(sv[1][0], sv[1][1]), fmaxf(sv[1][2], sv[1][3]));
    float m2 = fmaxf(fmaxf(sv[2][0], sv[2][1]), fmaxf(sv[2][2], sv[2][3]));
    float m3 = fmaxf(fmaxf(sv[3][0], sv[3][1]), fmaxf(sv[3][2], sv[3][3]));
    const float mx = fmaxf(fmaxf(m0, m1), fmaxf(m2, m3));

    if (__any(mx > m_r + 8.0f)) {
      float mc = fmaxf(mx, __shfl_xor(mx, 16));
      mc = fmaxf(mc, __shfl_xor(mc, 32));
      const float mnew = fmaxf(m_r, mc);
      const float alpha = __builtin_amdgcn_exp2f(m_r - mnew);
      m_r = mnew;
      l_lane *= alpha;
      #pragma unroll
      for (int sub = 0; sub < 4; ++sub)
        #pragma unroll
        for (int r = 0; r < 4; ++r) o[sub][r] *= alpha;
    }

    // exp + pack: P chunk c is directly the 16x16x16 B-operand
    half4 p4[4];
    #pragma unroll
    for (int c = 0; c < 4; ++c) {
      const float p0 = __builtin_amdgcn_exp2f(sv[c][0] - m_r);
      const float p1 = __builtin_amdgcn_exp2f(sv[c][1] - m_r);
      const float p2 = __builtin_amdgcn_exp2f(sv[c][2] - m_r);
      const float p3 = __builtin_amdgcn_exp2f(sv[c][3] - m_r);
      l_lane += (p0 + p1) + (p2 + p3);
      const fp16x2 a01 = __builtin_amdgcn_cvt_pkrtz(p0, p1);
      const fp16x2 a23 = __builtin_amdgcn_cvt_pkrtz(p2, p3);
      half4 pv;
      pv[0] = (_Float16)a01[0]; pv[1] = (_Float16)a01[1];
      pv[2] = (_Float16)a23[0]; pv[3] = (_Float16)a23[1];
      p4[c] = pv;
    }

    // stage next tile (regs) into the other buffer — hidden under PV.
    // Safe: every wave passed the barrier that ended the last iter that
    // READ buf^1 before any wave reaches this point.
    if (kt < 31) {
      *(half8*)&Kh[buf ^ 1][sr][sc] = pK;
      *(half8*)&Kl[buf ^ 1][sr][sc] = pL;
      *(half8*)&Vs[buf ^ 1][sr][vsw] = pV;
    }

    // PV: o[sub] covers d = sub*16 + (q4*4+r), q = l16
    __builtin_amdgcn_s_setprio(1);
    #pragma unroll
    for (int sub = 0; sub < 4; ++sub) {
      const half8 v01 = *(const half8*)&Vs[buf][sub * 16 + l16][vch0];
      const half8 v23 = *(const half8*)&Vs[buf][sub * 16 + l16][vch1];
      const half4 va0 = {v01[0], v01[1], v01[2], v01[3]};
      const half4 va1 = {v01[4], v01[5], v01[6], v01[7]};
      const half4 va2 = {v23[0], v23[1], v23[2], v23[3]};
      const half4 va3 = {v23[4], v23[5], v23[6], v23[7]};
      o[sub] = mfma16k16(va0, p4[0], o[sub]);
      o[sub] = mfma16k16(va1, p4[1], o[sub]);
      o[sub] = mfma16k16(va2, p4[2], o[sub]);
      o[sub] = mfma16k16(va3, p4[3], o[sub]);
    }
    __builtin_amdgcn_s_setprio(0);

    __syncthreads();   // single barrier per iteration

    // prefetch tile kt+2 (consumed by the write in the next body)
    if (kt < 30) {
      const int k2 = (kt + 2) * 64;
      const int gk = (bh * SS + k2 + sr) * DHH + sc;
      pK = *(const half8*)(kh + gk);
      pL = *(const half8*)(kl + gk);
      pV = *(const half8*)(vt + (bh * DHH + sr) * SS + k2 + sc);
    }
  };

  #pragma unroll 1
  for (int kt = 0; kt < 32; kt += 2) {
    body(0, kt);
    body(1, kt + 1);
  }

  // epilogue: reduce per-lane psum across the q-column's 4 lane groups
  float lsum = l_lane;
  lsum += __shfl_xor(lsum, 16);
  lsum += __shfl_xor(lsum, 32);
  const float inv = 1.0f / lsum;
  const int s = qt * 128 + wid * 16 + l16;
  #pragma unroll
  for (int sub = 0; sub < 4; ++sub) {
    half4 ov;
    #pragma unroll
    for (int r = 0; r < 4; ++r) ov[r] = (_Float16)(o[sub][r] * inv);
    *(half4*)(agg + (b * SS + s) * (HH * DHH) + h * DHH + sub * 16 + q4 * 4) = ov;
  }
}

// ---------------------------------------------------------------------------
// Kernel 3: output projection (R16 ring form, kept to get its isolated
// number: 8 waves/512 threads, 4-buffer ring, counted vmcnt 4/4/2/0).
// ---------------------------------------------------------------------------
__global__ __launch_bounds__(512) void out_gemm_kernel(
    const _Float16* __restrict__ agg, const _Float16* __restrict__ Wot,
    float* __restrict__ out)
{
  __shared__ alignas(16) _Float16 sbuf[4][2][128 * 32];   // 64 KB
  const int n0 = blockIdx.x * 128;
  const int m0 = blockIdx.y * 128;
  const int t = (int)threadIdx.x;
  const int lane = t & 63, wid = t >> 6;          // wid in [0,8)
  const int l16 = lane & 15, q4 = lane >> 4;
  const int mw = (wid & 3) * 32, nw = (wid >> 2) * 64;

  const int g  = (lane & 7) ^ ((lane >> 3) & 7);
  const int grow  = (lane >> 3) * 2 + (g >> 2);
  const int gcol8 = (g & 3) * 8;
  const int laneoff = (l16 >> 1) * 128 + (((((l16 & 1) << 2) | q4) ^ (l16 >> 1)) * 16);

  const int arr = wid & 1;
  const int rowq = (wid >> 1) * 32;
  const _Float16* src = (arr == 0) ? (agg + m0 * 1024) : (Wot + n0 * 1024);
  const _Float16* gsrc = src + (rowq + grow) * 1024 + gcol8;

  const floatx4 z4 = {0.0f, 0.0f, 0.0f, 0.0f};
  floatx4 acc[2][4];
  #pragma unroll
  for (int mi = 0; mi < 2; ++mi)
    #pragma unroll
    for (int ni = 0; ni < 4; ++ni) acc[mi][ni] = z4;

  auto stage = [&](int buf, int kt2) {
    const _Float16* gp = gsrc + kt2 * 32;
    _Float16* dst = &sbuf[buf][arr][rowq * 32];
    #pragma unroll
    for (int j = 0; j < 2; ++j)
      dma16(gp + j * 16 * 1024, dst + j * 16 * 32);
  };

  auto compute = [&](int buf) {
    const char* sA = (const char*)&sbuf[buf][0][0];
    const char* sB = (const char*)&sbuf[buf][1][0];
    half8 a_f[2];
    #pragma unroll
    for (int mi = 0; mi < 2; ++mi)
      a_f[mi] = *(const half8*)(sA + (mw + mi * 16) * 64 + laneoff);
    #pragma unroll
    for (int ni = 0; ni < 4; ++ni) {
      const half8 b_f = *(const half8*)(sB + (nw + ni * 16) * 64 + laneoff);
      #pragma unroll
      for (int mi = 0; mi < 2; ++mi)
        acc[mi][ni] = mfma16(a_f[mi], b_f, acc[mi][ni]);
    }
  };

  stage(0, 0);
  stage(1, 1);
  stage(2, 2);

#define OUT_PHASE(P, BUF, VC)                                  \
  asm volatile("s_waitcnt vmcnt(" #VC ")" ::: "memory");       \
  __builtin_amdgcn_s_barrier();                                \
  if ((P) + 3 < 32) stage(((P) + 3) & 3, (P) + 3);             \
  compute(BUF);

  #pragma unroll 1
  for (int p4 = 0; p4 < 28; p4 += 4) {
    OUT_PHASE(p4 + 0, 0, 4)
    OUT_PHASE(p4 + 1, 1, 4)
    OUT_PHASE(p4 + 2, 2, 4)
    OUT_PHASE(p4 + 3, 3, 4)
  }
  OUT_PHASE(28, 0, 4)
  OUT_PHASE(29, 1, 4)
  OUT_PHASE(30, 2, 2)
  OUT_PHASE(31, 3, 0)
#undef OUT_PHASE

  #pragma unroll
  for (int ni = 0; ni < 4; ++ni)
    #pragma unroll
    for (int mi = 0; mi < 2; ++mi)
      #pragma unroll
      for (int r = 0; r < 4; ++r)
        out[(m0 + mw + mi * 16 + q4 * 4 + r) * 1024 + n0 + nw + ni * 16 + l16] =
            acc[mi][ni][r];
}

// ---------------------------------------------------------------------------
extern "C" void kernel_launch(void* const* d_in, const int* in_sizes, int n_in,
                              void* d_out, int out_size, void* d_ws, size_t ws_size,
                              hipStream_t stream)
{
  const float* tokens = (const float*)d_in[0];
  const float* wq = (const float*)d_in[1];
  const float* wk = (const float*)d_in[2];
  const float* wv = (const float*)d_in[3];
  const float* wo = (const float*)d_in[4];
  float* out = (float*)d_out;

  char* ws = (char*)d_ws;
  // layout (bytes):
  //   qh 0          ql 8388608    kh 16777216   kl 25165824   vt 33554432
  //   Wh 41943040 (6291456)   Wl 48234496 (6291456)   Wot 54525952 (2097152)
  //   th 56623104 (8388608)   tl 65011712 (8388608)      total 73400320
  //   agg aliases th (th dead after qkv_gemm)
  _Float16* qh  = (_Float16*)(ws);
  _Float16* ql  = (_Float16*)(ws + 8388608);
  _Float16* kh  = (_Float16*)(ws + 16777216);
  _Float16* kl  = (_Float16*)(ws + 25165824);
  _Float16* vt  = (_Float16*)(ws + 33554432);
  _Float16* Wh  = (_Float16*)(ws + 41943040);
  _Float16* Wl  = (_Float16*)(ws + 48234496);
  _Float16* Wot = (_Float16*)(ws + 54525952);
  _Float16* th  = (_Float16*)(ws + 56623104);
  _Float16* tl  = (_Float16*)(ws + 65011712);
  _Float16* agg = (_Float16*)(ws + 56623104);

  convert_kernel<<<dim3(16, 16, 4), 256, 0, stream>>>(wq, wk, wv, wo, Wh, Wl, Wot);
  tokens_split_kernel<<<2048, 256, 0, stream>>>(tokens, th, tl);
  qkv_gemm_kernel<<<dim3(24, 32), 512, 0, stream>>>(th, tl, Wh, Wl, qh, ql, kh, kl, vt);
  attn_kernel<<<dim3(16, 16, 2), 512, 0, stream>>>(qh, ql, kh, kl, vt, agg);
  out_gemm_kernel<<<dim3(8, 32), 512, 0, stream>>>(agg, Wot, out);
}

// Round 12
// 263.386 us; speedup vs baseline: 1.3055x; 1.0170x over previous
//
#include <hip/hip_runtime.h>
#include <hip/hip_fp16.h>
#include <stdint.h>

// Problem constants
#define BB 2
#define HH 16
#define SS 2048
#define DD 1024
#define DHH 64
// SCALE * log2(e): logits computed directly in log2 domain
#define QSCALE 0.18033688011112042f

typedef _Float16 half8 __attribute__((ext_vector_type(8)));
typedef _Float16 half4 __attribute__((ext_vector_type(4)));
typedef __fp16 fp16x2 __attribute__((ext_vector_type(2)));
typedef float floatx4 __attribute__((ext_vector_type(4)));

__device__ __forceinline__ floatx4 mfma16(half8 a, half8 b, floatx4 c) {
  return __builtin_amdgcn_mfma_f32_16x16x32_f16(a, b, c, 0, 0, 0);
}
__device__ __forceinline__ floatx4 mfma16k16(half4 a, half4 b, floatx4 c) {
  return __builtin_amdgcn_mfma_f32_16x16x16f16(a, b, c, 0, 0, 0);
}

// Async global->LDS DMA, 16B per lane (1KB per wave-issue).
__device__ __forceinline__ void dma16(const _Float16* g, _Float16* l) {
  __builtin_amdgcn_global_load_lds(
      (const __attribute__((address_space(1))) uint32_t*)g,
      (__attribute__((address_space(3))) uint32_t*)l,
      16, 0, 0);
}

// ---------------------------------------------------------------------------
// Kernel 0a: weight conversion (once per call).
// ---------------------------------------------------------------------------
__global__ __launch_bounds__(256) void convert_kernel(
    const float* __restrict__ wq, const float* __restrict__ wk,
    const float* __restrict__ wv, const float* __restrict__ wo,
    _Float16* __restrict__ Wh, _Float16* __restrict__ Wl,
    _Float16* __restrict__ Wot)
{
  __shared__ float St[64][68];
  const int kt = blockIdx.x;
  const int hy = blockIdx.y;
  const int z  = blockIdx.z;
  const int t  = (int)threadIdx.x;
  const int k0 = kt * 64;

  const float* src = (z == 0) ? (wq + hy * (DD * DHH))
                   : (z == 1) ? (wk + hy * (DD * DHH))
                   : (z == 2) ? (wv + hy * (DD * DHH))
                   : wo;

  const int rr = t >> 4, cc = (t & 15) * 4;
  if (z < 3) {
    #pragma unroll
    for (int i = 0; i < 4; ++i)
      *(floatx4*)&St[rr + 16 * i][cc] =
          *(const floatx4*)(src + (k0 + rr + 16 * i) * DHH + cc);
  } else {
    const int d0 = hy * 64;
    #pragma unroll
    for (int i = 0; i < 4; ++i)
      *(floatx4*)&St[rr + 16 * i][cc] =
          *(const floatx4*)(src + (k0 + rr + 16 * i) * 1024 + d0 + cc);
  }
  __syncthreads();

  const int e = t >> 2, kc = (t & 3) * 16;
  if (z < 3) {
    const int n = z * 1024 + hy * 64 + e;
    half8 hi0, hi1, lo0, lo1;
    #pragma unroll
    for (int u = 0; u < 16; ++u) {
      float x = St[kc + u][e];
      _Float16 hh = (_Float16)x;
      _Float16 ll = (_Float16)(x - (float)hh);
      if (u < 8) { hi0[u] = hh; lo0[u] = ll; }
      else       { hi1[u - 8] = hh; lo1[u - 8] = ll; }
    }
    *(half8*)(Wh + n * 1024 + k0 + kc)     = hi0;
    *(half8*)(Wh + n * 1024 + k0 + kc + 8) = hi1;
    *(half8*)(Wl + n * 1024 + k0 + kc)     = lo0;
    *(half8*)(Wl + n * 1024 + k0 + kc + 8) = lo1;
  } else {
    const int d0 = hy * 64;
    half8 hi0, hi1;
    #pragma unroll
    for (int u = 0; u < 16; ++u) {
      _Float16 hh = (_Float16)St[kc + u][e];
      if (u < 8) hi0[u] = hh; else hi1[u - 8] = hh;
    }
    *(half8*)(Wot + (d0 + e) * 1024 + k0 + kc)     = hi0;
    *(half8*)(Wot + (d0 + e) * 1024 + k0 + kc + 8) = hi1;
  }
}

// ---------------------------------------------------------------------------
// Kernel 0b: token split (elementwise, memory-bound).
// ---------------------------------------------------------------------------
__global__ __launch_bounds__(256) void tokens_split_kernel(
    const float* __restrict__ tokens,
    _Float16* __restrict__ th, _Float16* __restrict__ tl)
{
  const int i = ((int)blockIdx.x * 256 + (int)threadIdx.x) * 8;
  floatx4 x0 = *(const floatx4*)(tokens + i);
  floatx4 x1 = *(const floatx4*)(tokens + i + 4);
  half8 h, l;
  #pragma unroll
  for (int j = 0; j < 8; ++j) {
    float x = (j < 4) ? x0[j] : x1[j - 4];
    _Float16 hh = (_Float16)x;
    h[j] = hh;
    l[j] = (_Float16)(x - (float)hh);
  }
  *(half8*)(th + i) = h;
  *(half8*)(tl + i) = l;
}

// ---------------------------------------------------------------------------
// Kernel 1: fused QKV GEMM (unchanged R15: 8-wave, 4-buffer ring,
// counted vmcnt -> s_barrier -> stage(p+3) -> compute(p)).
// ---------------------------------------------------------------------------
__global__ __launch_bounds__(512) void qkv_gemm_kernel(
    const _Float16* __restrict__ th, const _Float16* __restrict__ tl,
    const _Float16* __restrict__ Wh, const _Float16* __restrict__ Wl,
    _Float16* __restrict__ qh, _Float16* __restrict__ ql,
    _Float16* __restrict__ kh, _Float16* __restrict__ kl,
    _Float16* __restrict__ vt)
{
  __shared__ alignas(16) _Float16 sbuf[4][4][128 * 32];   // 128 KB

  const int n0 = blockIdx.x * 128;   // 0..23
  const int m0 = blockIdx.y * 128;   // 0..31
  const int zb = n0 >> 10;           // 0=q, 1=k, 2=v
  const bool is_v = (zb == 2);
  const int t = (int)threadIdx.x;
  const int lane = t & 63, wid = t >> 6;          // wid in [0,8)
  const int l16 = lane & 15, q4 = lane >> 4;
  const int mw = (wid & 3) * 32, nw = (wid >> 2) * 64;

  const int g  = (lane & 7) ^ ((lane >> 3) & 7);
  const int grow  = (lane >> 3) * 2 + (g >> 2);
  const int gcol8 = (g & 3) * 8;
  const int laneoff = (l16 >> 1) * 128 + (((((l16 & 1) << 2) | q4) ^ (l16 >> 1)) * 16);

  const int arr = wid & 3;
  const int rowb = (wid >> 2) * 64;
  const _Float16* src = (arr == 0) ? (th + m0 * 1024)
                      : (arr == 1) ? (Wh + n0 * 1024)
                      : (arr == 2) ? (Wl + n0 * 1024)
                      :              (tl + m0 * 1024);
  const bool stage_active = !(is_v && arr == 3);
  const _Float16* gsrc = src + (rowb + grow) * 1024 + gcol8;

  const floatx4 z4 = {0.0f, 0.0f, 0.0f, 0.0f};
  floatx4 acc[2][4];
  #pragma unroll
  for (int mi = 0; mi < 2; ++mi)
    #pragma unroll
    for (int ni = 0; ni < 4; ++ni) acc[mi][ni] = z4;

  auto stage = [&](int buf, int kt2) {
    if (stage_active) {
      const _Float16* gp = gsrc + kt2 * 32;
      _Float16* dst = &sbuf[buf][arr][rowb * 32];
      #pragma unroll
      for (int j = 0; j < 4; ++j)
        dma16(gp + j * 16 * 1024, dst + j * 16 * 32);
    }
  };

  auto compute = [&](int buf) {
    const char* sAh = (const char*)&sbuf[buf][0][0];
    const char* sBh = (const char*)&sbuf[buf][1][0];
    const char* sBl = (const char*)&sbuf[buf][2][0];
    const char* sAl = (const char*)&sbuf[buf][3][0];
    half8 a_h[2], b_h[4], b_l[4];
    #pragma unroll
    for (int mi = 0; mi < 2; ++mi)
      a_h[mi] = *(const half8*)(sAh + (mw + mi * 16) * 64 + laneoff);
    #pragma unroll
    for (int ni = 0; ni < 4; ++ni) {
      b_h[ni] = *(const half8*)(sBh + (nw + ni * 16) * 64 + laneoff);
      b_l[ni] = *(const half8*)(sBl + (nw + ni * 16) * 64 + laneoff);
    }
    #pragma unroll
    for (int ni = 0; ni < 4; ++ni)
      #pragma unroll
      for (int mi = 0; mi < 2; ++mi)
        acc[mi][ni] = mfma16(a_h[mi], b_h[ni], acc[mi][ni]);
    if (!is_v) {
      half8 a_l[2];
      #pragma unroll
      for (int mi = 0; mi < 2; ++mi)
        a_l[mi] = *(const half8*)(sAl + (mw + mi * 16) * 64 + laneoff);
      #pragma unroll
      for (int ni = 0; ni < 4; ++ni)
        #pragma unroll
        for (int mi = 0; mi < 2; ++mi)
          acc[mi][ni] = mfma16(a_l[mi], b_h[ni], acc[mi][ni]);
    }
    #pragma unroll
    for (int ni = 0; ni < 4; ++ni)
      #pragma unroll
      for (int mi = 0; mi < 2; ++mi)
        acc[mi][ni] = mfma16(a_h[mi], b_l[ni], acc[mi][ni]);
  };

  stage(0, 0);
  stage(1, 1);
  stage(2, 2);

#define QKV_PHASE(P, BUF, VC)                                  \
  asm volatile("s_waitcnt vmcnt(" #VC ")" ::: "memory");       \
  __builtin_amdgcn_s_barrier();                                \
  if ((P) + 3 < 32) stage(((P) + 3) & 3, (P) + 3);             \
  compute(BUF);

  #pragma unroll 1
  for (int p4 = 0; p4 < 28; p4 += 4) {
    QKV_PHASE(p4 + 0, 0, 8)
    QKV_PHASE(p4 + 1, 1, 8)
    QKV_PHASE(p4 + 2, 2, 8)
    QKV_PHASE(p4 + 3, 3, 8)
  }
  QKV_PHASE(28, 0, 8)
  QKV_PHASE(29, 1, 8)
  QKV_PHASE(30, 2, 4)
  QKV_PHASE(31, 3, 0)
#undef QKV_PHASE

  #pragma unroll
  for (int ni = 0; ni < 4; ++ni) {
    const int ncol = n0 + nw + ni * 16;
    const int h = (ncol >> 6) & 15;
    const int e = (ncol & 63) + l16;
    #pragma unroll
    for (int mi = 0; mi < 2; ++mi) {
      #pragma unroll
      for (int r = 0; r < 4; ++r) {
        const int grow2 = m0 + mw + mi * 16 + q4 * 4 + r;
        const int b = grow2 >> 11, s = grow2 & 2047;
        const float v = acc[mi][ni][r];
        const int qkidx = ((b * HH + h) * SS + s) * DHH + e;
        if (zb == 0) {
          const float vs = v * QSCALE;
          const _Float16 hh = (_Float16)vs;
          qh[qkidx] = hh;
          ql[qkidx] = (_Float16)(vs - (float)hh);
        } else if (zb == 1) {
          const _Float16 hh = (_Float16)v;
          kh[qkidx] = hh;
          kl[qkidx] = (_Float16)(v - (float)hh);
        } else {
          // key-permuted V layout within each 64-key block (see attn PV).
          const int sl = s & 63;
          const int sp = (s & ~63) | ((sl & 48) >> 2) | ((sl & 12) << 2) | (sl & 3);
          vt[((b * HH + h) * DHH + e) * SS + sp] = (_Float16)v;
        }
      }
    }
  }
}

// ---------------------------------------------------------------------------
// Kernel 2: flash attention.  R18 = R17 + K-tile XOR swizzle.
// Kh/Kl stored unpadded [64][64] with the SAME 16B-chunk swizzle as Vs
// (write chunk (t&7)^(sr&7); read chunks q4^(l16&7), (q4+4)^(l16&7)).
// The old [64][72] padded layout put 8 lanes per 4-bank group on every
// K-frag read (1.26e7 conflict cycles ~= 20% of attn); swizzled layout
// lands exactly 2 lanes per bank-phase = free (m136).  LDS 53.2->49.2 KB.
// ---------------------------------------------------------------------------
__global__ __launch_bounds__(512) void attn_kernel(
    const _Float16* __restrict__ qh, const _Float16* __restrict__ ql,
    const _Float16* __restrict__ kh, const _Float16* __restrict__ kl,
    const _Float16* __restrict__ vt, _Float16* __restrict__ agg)
{
  __shared__ _Float16 Kh[2][64][64], Kl[2][64][64];   // 32 KB (swizzled)
  __shared__ _Float16 Vs[2][64][64];                  // 16 KB (swizzled)

  const int qt = blockIdx.x;
  const int h  = blockIdx.y;
  const int b  = blockIdx.z;
  const int bh = b * HH + h;
  const int t = (int)threadIdx.x;
  const int lane = t & 63, wid = t >> 6;
  const int l16 = lane & 15, q4 = lane >> 4;

  const int sr = t >> 3, sc = (t & 7) * 8;
  const int vsw = ((t & 7) ^ (sr & 7)) * 8;           // swizzled write col

  // swizzled V read chunks (per lane, c2 = 0/1)
  const int vch0 = ((2 * q4 + 0) ^ (l16 & 7)) * 8;
  const int vch1 = ((2 * q4 + 1) ^ (l16 & 7)) * 8;
  // swizzled K read chunks (frag halves at +0 and +64B => chunks q4, q4+4)
  const int kch0 = (q4 ^ (l16 & 7)) * 8;
  const int kch1 = ((q4 + 4) ^ (l16 & 7)) * 8;

  half8 qfh[2], qfl[2];
  {
    const int s = qt * 128 + wid * 16 + l16;
    const int base = (bh * SS + s) * DHH + q4 * 8;
    qfh[0] = *(const half8*)(qh + base);
    qfh[1] = *(const half8*)(qh + base + 32);
    qfl[0] = *(const half8*)(ql + base);
    qfl[1] = *(const half8*)(ql + base + 32);
  }

  const floatx4 z4 = {0.0f, 0.0f, 0.0f, 0.0f};
  floatx4 o[4];
  #pragma unroll
  for (int i = 0; i < 4; ++i) o[i] = z4;
  float m_r = -1e30f;
  float l_lane = 0.0f;

  half8 pK, pL, pV;
  // preload tile 0, stage it, then preload tile 1
  {
    const int gk = (bh * SS + sr) * DHH + sc;
    pK = *(const half8*)(kh + gk);
    pL = *(const half8*)(kl + gk);
    pV = *(const half8*)(vt + (bh * DHH + sr) * SS + sc);
  }
  *(half8*)&Kh[0][sr][vsw] = pK;
  *(half8*)&Kl[0][sr][vsw] = pL;
  *(half8*)&Vs[0][sr][vsw] = pV;
  __syncthreads();
  {
    const int gk = (bh * SS + 64 + sr) * DHH + sc;
    pK = *(const half8*)(kh + gk);
    pL = *(const half8*)(kl + gk);
    pV = *(const half8*)(vt + (bh * DHH + sr) * SS + 64 + sc);
  }

  auto body = [&](int buf, int kt) {
    // QK^T in log2 domain
    floatx4 sv[4];
    __builtin_amdgcn_s_setprio(1);
    #pragma unroll
    for (int sub = 0; sub < 4; ++sub) {
      const half8 ah0 = *(const half8*)&Kh[buf][sub * 16 + l16][kch0];
      const half8 ah1 = *(const half8*)&Kh[buf][sub * 16 + l16][kch1];
      const half8 al0 = *(const half8*)&Kl[buf][sub * 16 + l16][kch0];
      const half8 al1 = *(const half8*)&Kl[buf][sub * 16 + l16][kch1];
      floatx4 s4 = z4;
      s4 = mfma16(ah0, qfh[0], s4);
      s4 = mfma16(ah1, qfh[1], s4);
      s4 = mfma16(al0, qfh[0], s4);
      s4 = mfma16(al1, qfh[1], s4);
      s4 = mfma16(ah0, qfl[0], s4);
      s4 = mfma16(ah1, qfl[1], s4);
      sv[sub] = s4;
    }
    __builtin_amdgcn_s_setprio(0);

    // per-lane max only; cross-lane work deferred to the rare rescale path
    float m0 = fmaxf(fmaxf(sv[0][0], sv[0][1]), fmaxf(sv[0][2], sv[0][3]));
    float m1 = fmaxf(fmaxf(sv[1][0], sv[1][1]), fmaxf(sv[1][2], sv[1][3]));
    float m2 = fmaxf(fmaxf(sv[2][0], sv[2][1]), fmaxf(sv[2][2], sv[2][3]));
    float m3 = fmaxf(fmaxf(sv[3][0], sv[3][1]), fmaxf(sv[3][2], sv[3][3]));
    const float mx = fmaxf(fmaxf(m0, m1), fmaxf(m2, m3));

    if (__any(mx > m_r + 8.0f)) {
      float mc = fmaxf(mx, __shfl_xor(mx, 16));
      mc = fmaxf(mc, __shfl_xor(mc, 32));
      const float mnew = fmaxf(m_r, mc);
      const float alpha = __builtin_amdgcn_exp2f(m_r - mnew);
      m_r = mnew;
      l_lane *= alpha;
      #pragma unroll
      for (int sub = 0; sub < 4; ++sub)
        #pragma unroll
        for (int r = 0; r < 4; ++r) o[sub][r] *= alpha;
    }

    // exp + pack: P chunk c is directly the 16x16x16 B-operand
    half4 p4[4];
    #pragma unroll
    for (int c = 0; c < 4; ++c) {
      const float p0 = __builtin_amdgcn_exp2f(sv[c][0] - m_r);
      const float p1 = __builtin_amdgcn_exp2f(sv[c][1] - m_r);
      const float p2 = __builtin_amdgcn_exp2f(sv[c][2] - m_r);
      const float p3 = __builtin_amdgcn_exp2f(sv[c][3] - m_r);
      l_lane += (p0 + p1) + (p2 + p3);
      const fp16x2 a01 = __builtin_amdgcn_cvt_pkrtz(p0, p1);
      const fp16x2 a23 = __builtin_amdgcn_cvt_pkrtz(p2, p3);
      half4 pv;
      pv[0] = (_Float16)a01[0]; pv[1] = (_Float16)a01[1];
      pv[2] = (_Float16)a23[0]; pv[3] = (_Float16)a23[1];
      p4[c] = pv;
    }

    // stage next tile (regs) into the other buffer — hidden under PV.
    // Safe: every wave passed the barrier that ended the last iter that
    // READ buf^1 before any wave reaches this point.
    if (kt < 31) {
      *(half8*)&Kh[buf ^ 1][sr][vsw] = pK;
      *(half8*)&Kl[buf ^ 1][sr][vsw] = pL;
      *(half8*)&Vs[buf ^ 1][sr][vsw] = pV;
    }

    // PV: o[sub] covers d = sub*16 + (q4*4+r), q = l16
    __builtin_amdgcn_s_setprio(1);
    #pragma unroll
    for (int sub = 0; sub < 4; ++sub) {
      const half8 v01 = *(const half8*)&Vs[buf][sub * 16 + l16][vch0];
      const half8 v23 = *(const half8*)&Vs[buf][sub * 16 + l16][vch1];
      const half4 va0 = {v01[0], v01[1], v01[2], v01[3]};
      const half4 va1 = {v01[4], v01[5], v01[6], v01[7]};
      const half4 va2 = {v23[0], v23[1], v23[2], v23[3]};
      const half4 va3 = {v23[4], v23[5], v23[6], v23[7]};
      o[sub] = mfma16k16(va0, p4[0], o[sub]);
      o[sub] = mfma16k16(va1, p4[1], o[sub]);
      o[sub] = mfma16k16(va2, p4[2], o[sub]);
      o[sub] = mfma16k16(va3, p4[3], o[sub]);
    }
    __builtin_amdgcn_s_setprio(0);

    __syncthreads();   // single barrier per iteration

    // prefetch tile kt+2 (consumed by the write in the next body)
    if (kt < 30) {
      const int k2 = (kt + 2) * 64;
      const int gk = (bh * SS + k2 + sr) * DHH + sc;
      pK = *(const half8*)(kh + gk);
      pL = *(const half8*)(kl + gk);
      pV = *(const half8*)(vt + (bh * DHH + sr) * SS + k2 + sc);
    }
  };

  #pragma unroll 1
  for (int kt = 0; kt < 32; kt += 2) {
    body(0, kt);
    body(1, kt + 1);
  }

  // epilogue: reduce per-lane psum across the q-column's 4 lane groups
  float lsum = l_lane;
  lsum += __shfl_xor(lsum, 16);
  lsum += __shfl_xor(lsum, 32);
  const float inv = 1.0f / lsum;
  const int s = qt * 128 + wid * 16 + l16;
  #pragma unroll
  for (int sub = 0; sub < 4; ++sub) {
    half4 ov;
    #pragma unroll
    for (int r = 0; r < 4; ++r) ov[r] = (_Float16)(o[sub][r] * inv);
    *(half4*)(agg + (b * SS + s) * (HH * DHH) + h * DHH + sub * 16 + q4 * 4) = ov;
  }
}

// ---------------------------------------------------------------------------
// Kernel 3: output projection (R16 ring form, proven R17: 8 waves/512
// threads, 4-buffer ring, counted vmcnt 4/4/2/0).
// ---------------------------------------------------------------------------
__global__ __launch_bounds__(512) void out_gemm_kernel(
    const _Float16* __restrict__ agg, const _Float16* __restrict__ Wot,
    float* __restrict__ out)
{
  __shared__ alignas(16) _Float16 sbuf[4][2][128 * 32];   // 64 KB
  const int n0 = blockIdx.x * 128;
  const int m0 = blockIdx.y * 128;
  const int t = (int)threadIdx.x;
  const int lane = t & 63, wid = t >> 6;          // wid in [0,8)
  const int l16 = lane & 15, q4 = lane >> 4;
  const int mw = (wid & 3) * 32, nw = (wid >> 2) * 64;

  const int g  = (lane & 7) ^ ((lane >> 3) & 7);
  const int grow  = (lane >> 3) * 2 + (g >> 2);
  const int gcol8 = (g & 3) * 8;
  const int laneoff = (l16 >> 1) * 128 + (((((l16 & 1) << 2) | q4) ^ (l16 >> 1)) * 16);

  const int arr = wid & 1;
  const int rowq = (wid >> 1) * 32;
  const _Float16* src = (arr == 0) ? (agg + m0 * 1024) : (Wot + n0 * 1024);
  const _Float16* gsrc = src + (rowq + grow) * 1024 + gcol8;

  const floatx4 z4 = {0.0f, 0.0f, 0.0f, 0.0f};
  floatx4 acc[2][4];
  #pragma unroll
  for (int mi = 0; mi < 2; ++mi)
    #pragma unroll
    for (int ni = 0; ni < 4; ++ni) acc[mi][ni] = z4;

  auto stage = [&](int buf, int kt2) {
    const _Float16* gp = gsrc + kt2 * 32;
    _Float16* dst = &sbuf[buf][arr][rowq * 32];
    #pragma unroll
    for (int j = 0; j < 2; ++j)
      dma16(gp + j * 16 * 1024, dst + j * 16 * 32);
  };

  auto compute = [&](int buf) {
    const char* sA = (const char*)&sbuf[buf][0][0];
    const char* sB = (const char*)&sbuf[buf][1][0];
    half8 a_f[2];
    #pragma unroll
    for (int mi = 0; mi < 2; ++mi)
      a_f[mi] = *(const half8*)(sA + (mw + mi * 16) * 64 + laneoff);
    #pragma unroll
    for (int ni = 0; ni < 4; ++ni) {
      const half8 b_f = *(const half8*)(sB + (nw + ni * 16) * 64 + laneoff);
      #pragma unroll
      for (int mi = 0; mi < 2; ++mi)
        acc[mi][ni] = mfma16(a_f[mi], b_f, acc[mi][ni]);
    }
  };

  stage(0, 0);
  stage(1, 1);
  stage(2, 2);

#define OUT_PHASE(P, BUF, VC)                                  \
  asm volatile("s_waitcnt vmcnt(" #VC ")" ::: "memory");       \
  __builtin_amdgcn_s_barrier();                                \
  if ((P) + 3 < 32) stage(((P) + 3) & 3, (P) + 3);             \
  compute(BUF);

  #pragma unroll 1
  for (int p4 = 0; p4 < 28; p4 += 4) {
    OUT_PHASE(p4 + 0, 0, 4)
    OUT_PHASE(p4 + 1, 1, 4)
    OUT_PHASE(p4 + 2, 2, 4)
    OUT_PHASE(p4 + 3, 3, 4)
  }
  OUT_PHASE(28, 0, 4)
  OUT_PHASE(29, 1, 4)
  OUT_PHASE(30, 2, 2)
  OUT_PHASE(31, 3, 0)
#undef OUT_PHASE

  #pragma unroll
  for (int ni = 0; ni < 4; ++ni)
    #pragma unroll
    for (int mi = 0; mi < 2; ++mi)
      #pragma unroll
      for (int r = 0; r < 4; ++r)
        out[(m0 + mw + mi * 16 + q4 * 4 + r) * 1024 + n0 + nw + ni * 16 + l16] =
            acc[mi][ni][r];
}

// ---------------------------------------------------------------------------
extern "C" void kernel_launch(void* const* d_in, const int* in_sizes, int n_in,
                              void* d_out, int out_size, void* d_ws, size_t ws_size,
                              hipStream_t stream)
{
  const float* tokens = (const float*)d_in[0];
  const float* wq = (const float*)d_in[1];
  const float* wk = (const float*)d_in[2];
  const float* wv = (const float*)d_in[3];
  const float* wo = (const float*)d_in[4];
  float* out = (float*)d_out;

  char* ws = (char*)d_ws;
  // layout (bytes):
  //   qh 0          ql 8388608    kh 16777216   kl 25165824   vt 33554432
  //   Wh 41943040 (6291456)   Wl 48234496 (6291456)   Wot 54525952 (2097152)
  //   th 56623104 (8388608)   tl 65011712 (8388608)      total 73400320
  //   agg aliases th (th dead after qkv_gemm)
  _Float16* qh  = (_Float16*)(ws);
  _Float16* ql  = (_Float16*)(ws + 8388608);
  _Float16* kh  = (_Float16*)(ws + 16777216);
  _Float16* kl  = (_Float16*)(ws + 25165824);
  _Float16* vt  = (_Float16*)(ws + 33554432);
  _Float16* Wh  = (_Float16*)(ws + 41943040);
  _Float16* Wl  = (_Float16*)(ws + 48234496);
  _Float16* Wot = (_Float16*)(ws + 54525952);
  _Float16* th  = (_Float16*)(ws + 56623104);
  _Float16* tl  = (_Float16*)(ws + 65011712);
  _Float16* agg = (_Float16*)(ws + 56623104);

  convert_kernel<<<dim3(16, 16, 4), 256, 0, stream>>>(wq, wk, wv, wo, Wh, Wl, Wot);
  tokens_split_kernel<<<2048, 256, 0, stream>>>(tokens, th, tl);
  qkv_gemm_kernel<<<dim3(24, 32), 512, 0, stream>>>(th, tl, Wh, Wl, qh, ql, kh, kl, vt);
  attn_kernel<<<dim3(16, 16, 2), 512, 0, stream>>>(qh, ql, kh, kl, vt, agg);
  out_gemm_kernel<<<dim3(8, 32), 512, 0, stream>>>(agg, Wot, out);
}

// Round 13
// 244.936 us; speedup vs baseline: 1.4039x; 1.0753x over previous
//
#include <hip/hip_runtime.h>
#include <hip/hip_fp16.h>
#include <stdint.h>

// Problem constants
#define BB 2
#define HH 16
#define SS 2048
#define DD 1024
#define DHH 64
// SCALE * log2(e): logits computed directly in log2 domain
#define QSCALE 0.18033688011112042f

typedef _Float16 half8 __attribute__((ext_vector_type(8)));
typedef _Float16 half4 __attribute__((ext_vector_type(4)));
typedef __fp16 fp16x2 __attribute__((ext_vector_type(2)));
typedef float floatx4 __attribute__((ext_vector_type(4)));

__device__ __forceinline__ floatx4 mfma16(half8 a, half8 b, floatx4 c) {
  return __builtin_amdgcn_mfma_f32_16x16x32_f16(a, b, c, 0, 0, 0);
}
__device__ __forceinline__ floatx4 mfma16k16(half4 a, half4 b, floatx4 c) {
  return __builtin_amdgcn_mfma_f32_16x16x16f16(a, b, c, 0, 0, 0);
}

// Async global->LDS DMA, 16B per lane (1KB per wave-issue).
__device__ __forceinline__ void dma16(const _Float16* g, _Float16* l) {
  __builtin_amdgcn_global_load_lds(
      (const __attribute__((address_space(1))) uint32_t*)g,
      (__attribute__((address_space(3))) uint32_t*)l,
      16, 0, 0);
}

// ---------------------------------------------------------------------------
// Kernel 0a: weight conversion (once per call).
// ---------------------------------------------------------------------------
__global__ __launch_bounds__(256) void convert_kernel(
    const float* __restrict__ wq, const float* __restrict__ wk,
    const float* __restrict__ wv, const float* __restrict__ wo,
    _Float16* __restrict__ Wh, _Float16* __restrict__ Wl,
    _Float16* __restrict__ Wot)
{
  __shared__ float St[64][68];
  const int kt = blockIdx.x;
  const int hy = blockIdx.y;
  const int z  = blockIdx.z;
  const int t  = (int)threadIdx.x;
  const int k0 = kt * 64;

  const float* src = (z == 0) ? (wq + hy * (DD * DHH))
                   : (z == 1) ? (wk + hy * (DD * DHH))
                   : (z == 2) ? (wv + hy * (DD * DHH))
                   : wo;

  const int rr = t >> 4, cc = (t & 15) * 4;
  if (z < 3) {
    #pragma unroll
    for (int i = 0; i < 4; ++i)
      *(floatx4*)&St[rr + 16 * i][cc] =
          *(const floatx4*)(src + (k0 + rr + 16 * i) * DHH + cc);
  } else {
    const int d0 = hy * 64;
    #pragma unroll
    for (int i = 0; i < 4; ++i)
      *(floatx4*)&St[rr + 16 * i][cc] =
          *(const floatx4*)(src + (k0 + rr + 16 * i) * 1024 + d0 + cc);
  }
  __syncthreads();

  const int e = t >> 2, kc = (t & 3) * 16;
  if (z < 3) {
    const int n = z * 1024 + hy * 64 + e;
    half8 hi0, hi1, lo0, lo1;
    #pragma unroll
    for (int u = 0; u < 16; ++u) {
      float x = St[kc + u][e];
      _Float16 hh = (_Float16)x;
      _Float16 ll = (_Float16)(x - (float)hh);
      if (u < 8) { hi0[u] = hh; lo0[u] = ll; }
      else       { hi1[u - 8] = hh; lo1[u - 8] = ll; }
    }
    *(half8*)(Wh + n * 1024 + k0 + kc)     = hi0;
    *(half8*)(Wh + n * 1024 + k0 + kc + 8) = hi1;
    *(half8*)(Wl + n * 1024 + k0 + kc)     = lo0;
    *(half8*)(Wl + n * 1024 + k0 + kc + 8) = lo1;
  } else {
    const int d0 = hy * 64;
    half8 hi0, hi1;
    #pragma unroll
    for (int u = 0; u < 16; ++u) {
      _Float16 hh = (_Float16)St[kc + u][e];
      if (u < 8) hi0[u] = hh; else hi1[u - 8] = hh;
    }
    *(half8*)(Wot + (d0 + e) * 1024 + k0 + kc)     = hi0;
    *(half8*)(Wot + (d0 + e) * 1024 + k0 + kc + 8) = hi1;
  }
}

// ---------------------------------------------------------------------------
// Kernel 0b: token split (elementwise, memory-bound).
// ---------------------------------------------------------------------------
__global__ __launch_bounds__(256) void tokens_split_kernel(
    const float* __restrict__ tokens,
    _Float16* __restrict__ th, _Float16* __restrict__ tl)
{
  const int i = ((int)blockIdx.x * 256 + (int)threadIdx.x) * 8;
  floatx4 x0 = *(const floatx4*)(tokens + i);
  floatx4 x1 = *(const floatx4*)(tokens + i + 4);
  half8 h, l;
  #pragma unroll
  for (int j = 0; j < 8; ++j) {
    float x = (j < 4) ? x0[j] : x1[j - 4];
    _Float16 hh = (_Float16)x;
    h[j] = hh;
    l[j] = (_Float16)(x - (float)hh);
  }
  *(half8*)(th + i) = h;
  *(half8*)(tl + i) = l;
}

// ---------------------------------------------------------------------------
// Kernel 1: fused QKV GEMM.  R19: 2-buffer ring (64 KB -> 2 blocks/CU,
// 4 waves/SIMD) with counted vmcnt preserved via a two-barrier phase:
//   vmcnt(4)          <- tile p landed (tile p+1's 4 DMAs stay in flight)
//   s_barrier         <- collect all waves' vouchers (R13-proven order)
//   compute(p)
//   s_barrier         <- all reads of buf p&1 retired
//   stage(p+2 -> buf p&1)
// Prologue stages tiles 0,1.  Tail: phase 30 vmcnt(4), phase 31 vmcnt(0).
// R18's 4-buffer ring held qkv at 1 block/CU (Occ 19.7%, MfmaUtil 35) —
// exposed latency, not pipe saturation; this trades 1 barrier for 2x TLP.
// ---------------------------------------------------------------------------
__global__ __launch_bounds__(512) void qkv_gemm_kernel(
    const _Float16* __restrict__ th, const _Float16* __restrict__ tl,
    const _Float16* __restrict__ Wh, const _Float16* __restrict__ Wl,
    _Float16* __restrict__ qh, _Float16* __restrict__ ql,
    _Float16* __restrict__ kh, _Float16* __restrict__ kl,
    _Float16* __restrict__ vt)
{
  __shared__ alignas(16) _Float16 sbuf[2][4][128 * 32];   // 64 KB

  const int n0 = blockIdx.x * 128;   // 0..23
  const int m0 = blockIdx.y * 128;   // 0..31
  const int zb = n0 >> 10;           // 0=q, 1=k, 2=v
  const bool is_v = (zb == 2);
  const int t = (int)threadIdx.x;
  const int lane = t & 63, wid = t >> 6;          // wid in [0,8)
  const int l16 = lane & 15, q4 = lane >> 4;
  const int mw = (wid & 3) * 32, nw = (wid >> 2) * 64;

  const int g  = (lane & 7) ^ ((lane >> 3) & 7);
  const int grow  = (lane >> 3) * 2 + (g >> 2);
  const int gcol8 = (g & 3) * 8;
  const int laneoff = (l16 >> 1) * 128 + (((((l16 & 1) << 2) | q4) ^ (l16 >> 1)) * 16);

  const int arr = wid & 3;
  const int rowb = (wid >> 2) * 64;
  const _Float16* src = (arr == 0) ? (th + m0 * 1024)
                      : (arr == 1) ? (Wh + n0 * 1024)
                      : (arr == 2) ? (Wl + n0 * 1024)
                      :              (tl + m0 * 1024);
  const bool stage_active = !(is_v && arr == 3);
  const _Float16* gsrc = src + (rowb + grow) * 1024 + gcol8;

  const floatx4 z4 = {0.0f, 0.0f, 0.0f, 0.0f};
  floatx4 acc[2][4];
  #pragma unroll
  for (int mi = 0; mi < 2; ++mi)
    #pragma unroll
    for (int ni = 0; ni < 4; ++ni) acc[mi][ni] = z4;

  auto stage = [&](int buf, int kt2) {
    if (stage_active) {
      const _Float16* gp = gsrc + kt2 * 32;
      _Float16* dst = &sbuf[buf][arr][rowb * 32];
      #pragma unroll
      for (int j = 0; j < 4; ++j)
        dma16(gp + j * 16 * 1024, dst + j * 16 * 32);
    }
  };

  auto compute = [&](int buf) {
    const char* sAh = (const char*)&sbuf[buf][0][0];
    const char* sBh = (const char*)&sbuf[buf][1][0];
    const char* sBl = (const char*)&sbuf[buf][2][0];
    const char* sAl = (const char*)&sbuf[buf][3][0];
    half8 a_h[2], b_h[4], b_l[4];
    #pragma unroll
    for (int mi = 0; mi < 2; ++mi)
      a_h[mi] = *(const half8*)(sAh + (mw + mi * 16) * 64 + laneoff);
    #pragma unroll
    for (int ni = 0; ni < 4; ++ni) {
      b_h[ni] = *(const half8*)(sBh + (nw + ni * 16) * 64 + laneoff);
      b_l[ni] = *(const half8*)(sBl + (nw + ni * 16) * 64 + laneoff);
    }
    #pragma unroll
    for (int ni = 0; ni < 4; ++ni)
      #pragma unroll
      for (int mi = 0; mi < 2; ++mi)
        acc[mi][ni] = mfma16(a_h[mi], b_h[ni], acc[mi][ni]);
    if (!is_v) {
      half8 a_l[2];
      #pragma unroll
      for (int mi = 0; mi < 2; ++mi)
        a_l[mi] = *(const half8*)(sAl + (mw + mi * 16) * 64 + laneoff);
      #pragma unroll
      for (int ni = 0; ni < 4; ++ni)
        #pragma unroll
        for (int mi = 0; mi < 2; ++mi)
          acc[mi][ni] = mfma16(a_l[mi], b_h[ni], acc[mi][ni]);
    }
    #pragma unroll
    for (int ni = 0; ni < 4; ++ni)
      #pragma unroll
      for (int mi = 0; mi < 2; ++mi)
        acc[mi][ni] = mfma16(a_h[mi], b_l[ni], acc[mi][ni]);
  };

  stage(0, 0);
  stage(1, 1);

#define QKV_PHASE(P, BUF, VC)                                  \
  asm volatile("s_waitcnt vmcnt(" #VC ")" ::: "memory");       \
  __builtin_amdgcn_s_barrier();                                \
  compute(BUF);                                                \
  __builtin_amdgcn_s_barrier();                                \
  if ((P) + 2 < 32) stage(BUF, (P) + 2);

  #pragma unroll 1
  for (int p2 = 0; p2 < 30; p2 += 2) {
    QKV_PHASE(p2 + 0, 0, 4)
    QKV_PHASE(p2 + 1, 1, 4)
  }
  QKV_PHASE(30, 0, 4)
  QKV_PHASE(31, 1, 0)
#undef QKV_PHASE

  #pragma unroll
  for (int ni = 0; ni < 4; ++ni) {
    const int ncol = n0 + nw + ni * 16;
    const int h = (ncol >> 6) & 15;
    const int e = (ncol & 63) + l16;
    #pragma unroll
    for (int mi = 0; mi < 2; ++mi) {
      #pragma unroll
      for (int r = 0; r < 4; ++r) {
        const int grow2 = m0 + mw + mi * 16 + q4 * 4 + r;
        const int b = grow2 >> 11, s = grow2 & 2047;
        const float v = acc[mi][ni][r];
        const int qkidx = ((b * HH + h) * SS + s) * DHH + e;
        if (zb == 0) {
          const float vs = v * QSCALE;
          const _Float16 hh = (_Float16)vs;
          qh[qkidx] = hh;
          ql[qkidx] = (_Float16)(vs - (float)hh);
        } else if (zb == 1) {
          const _Float16 hh = (_Float16)v;
          kh[qkidx] = hh;
          kl[qkidx] = (_Float16)(v - (float)hh);
        } else {
          // key-permuted V layout within each 64-key block (see attn PV).
          const int sl = s & 63;
          const int sp = (s & ~63) | ((sl & 48) >> 2) | ((sl & 12) << 2) | (sl & 3);
          vt[((b * HH + h) * DHH + e) * SS + sp] = (_Float16)v;
        }
      }
    }
  }
}

// ---------------------------------------------------------------------------
// Kernel 2: flash attention (unchanged R18: K/V XOR-swizzled LDS, single
// barrier/iter, mid-body stage, raw exp2).
// ---------------------------------------------------------------------------
__global__ __launch_bounds__(512) void attn_kernel(
    const _Float16* __restrict__ qh, const _Float16* __restrict__ ql,
    const _Float16* __restrict__ kh, const _Float16* __restrict__ kl,
    const _Float16* __restrict__ vt, _Float16* __restrict__ agg)
{
  __shared__ _Float16 Kh[2][64][64], Kl[2][64][64];   // 32 KB (swizzled)
  __shared__ _Float16 Vs[2][64][64];                  // 16 KB (swizzled)

  const int qt = blockIdx.x;
  const int h  = blockIdx.y;
  const int b  = blockIdx.z;
  const int bh = b * HH + h;
  const int t = (int)threadIdx.x;
  const int lane = t & 63, wid = t >> 6;
  const int l16 = lane & 15, q4 = lane >> 4;

  const int sr = t >> 3, sc = (t & 7) * 8;
  const int vsw = ((t & 7) ^ (sr & 7)) * 8;           // swizzled write col

  // swizzled V read chunks (per lane, c2 = 0/1)
  const int vch0 = ((2 * q4 + 0) ^ (l16 & 7)) * 8;
  const int vch1 = ((2 * q4 + 1) ^ (l16 & 7)) * 8;
  // swizzled K read chunks (frag halves at +0 and +64B => chunks q4, q4+4)
  const int kch0 = (q4 ^ (l16 & 7)) * 8;
  const int kch1 = ((q4 + 4) ^ (l16 & 7)) * 8;

  half8 qfh[2], qfl[2];
  {
    const int s = qt * 128 + wid * 16 + l16;
    const int base = (bh * SS + s) * DHH + q4 * 8;
    qfh[0] = *(const half8*)(qh + base);
    qfh[1] = *(const half8*)(qh + base + 32);
    qfl[0] = *(const half8*)(ql + base);
    qfl[1] = *(const half8*)(ql + base + 32);
  }

  const floatx4 z4 = {0.0f, 0.0f, 0.0f, 0.0f};
  floatx4 o[4];
  #pragma unroll
  for (int i = 0; i < 4; ++i) o[i] = z4;
  float m_r = -1e30f;
  float l_lane = 0.0f;

  half8 pK, pL, pV;
  // preload tile 0, stage it, then preload tile 1
  {
    const int gk = (bh * SS + sr) * DHH + sc;
    pK = *(const half8*)(kh + gk);
    pL = *(const half8*)(kl + gk);
    pV = *(const half8*)(vt + (bh * DHH + sr) * SS + sc);
  }
  *(half8*)&Kh[0][sr][vsw] = pK;
  *(half8*)&Kl[0][sr][vsw] = pL;
  *(half8*)&Vs[0][sr][vsw] = pV;
  __syncthreads();
  {
    const int gk = (bh * SS + 64 + sr) * DHH + sc;
    pK = *(const half8*)(kh + gk);
    pL = *(const half8*)(kl + gk);
    pV = *(const half8*)(vt + (bh * DHH + sr) * SS + 64 + sc);
  }

  auto body = [&](int buf, int kt) {
    // QK^T in log2 domain
    floatx4 sv[4];
    __builtin_amdgcn_s_setprio(1);
    #pragma unroll
    for (int sub = 0; sub < 4; ++sub) {
      const half8 ah0 = *(const half8*)&Kh[buf][sub * 16 + l16][kch0];
      const half8 ah1 = *(const half8*)&Kh[buf][sub * 16 + l16][kch1];
      const half8 al0 = *(const half8*)&Kl[buf][sub * 16 + l16][kch0];
      const half8 al1 = *(const half8*)&Kl[buf][sub * 16 + l16][kch1];
      floatx4 s4 = z4;
      s4 = mfma16(ah0, qfh[0], s4);
      s4 = mfma16(ah1, qfh[1], s4);
      s4 = mfma16(al0, qfh[0], s4);
      s4 = mfma16(al1, qfh[1], s4);
      s4 = mfma16(ah0, qfl[0], s4);
      s4 = mfma16(ah1, qfl[1], s4);
      sv[sub] = s4;
    }
    __builtin_amdgcn_s_setprio(0);

    // per-lane max only; cross-lane work deferred to the rare rescale path
    float m0 = fmaxf(fmaxf(sv[0][0], sv[0][1]), fmaxf(sv[0][2], sv[0][3]));
    float m1 = fmaxf(fmaxf(sv[1][0], sv[1][1]), fmaxf(sv[1][2], sv[1][3]));
    float m2 = fmaxf(fmaxf(sv[2][0], sv[2][1]), fmaxf(sv[2][2], sv[2][3]));
    float m3 = fmaxf(fmaxf(sv[3][0], sv[3][1]), fmaxf(sv[3][2], sv[3][3]));
    const float mx = fmaxf(fmaxf(m0, m1), fmaxf(m2, m3));

    if (__any(mx > m_r + 8.0f)) {
      float mc = fmaxf(mx, __shfl_xor(mx, 16));
      mc = fmaxf(mc, __shfl_xor(mc, 32));
      const float mnew = fmaxf(m_r, mc);
      const float alpha = __builtin_amdgcn_exp2f(m_r - mnew);
      m_r = mnew;
      l_lane *= alpha;
      #pragma unroll
      for (int sub = 0; sub < 4; ++sub)
        #pragma unroll
        for (int r = 0; r < 4; ++r) o[sub][r] *= alpha;
    }

    // exp + pack: P chunk c is directly the 16x16x16 B-operand
    half4 p4[4];
    #pragma unroll
    for (int c = 0; c < 4; ++c) {
      const float p0 = __builtin_amdgcn_exp2f(sv[c][0] - m_r);
      const float p1 = __builtin_amdgcn_exp2f(sv[c][1] - m_r);
      const float p2 = __builtin_amdgcn_exp2f(sv[c][2] - m_r);
      const float p3 = __builtin_amdgcn_exp2f(sv[c][3] - m_r);
      l_lane += (p0 + p1) + (p2 + p3);
      const fp16x2 a01 = __builtin_amdgcn_cvt_pkrtz(p0, p1);
      const fp16x2 a23 = __builtin_amdgcn_cvt_pkrtz(p2, p3);
      half4 pv;
      pv[0] = (_Float16)a01[0]; pv[1] = (_Float16)a01[1];
      pv[2] = (_Float16)a23[0]; pv[3] = (_Float16)a23[1];
      p4[c] = pv;
    }

    // stage next tile (regs) into the other buffer — hidden under PV.
    if (kt < 31) {
      *(half8*)&Kh[buf ^ 1][sr][vsw] = pK;
      *(half8*)&Kl[buf ^ 1][sr][vsw] = pL;
      *(half8*)&Vs[buf ^ 1][sr][vsw] = pV;
    }

    // PV: o[sub] covers d = sub*16 + (q4*4+r), q = l16
    __builtin_amdgcn_s_setprio(1);
    #pragma unroll
    for (int sub = 0; sub < 4; ++sub) {
      const half8 v01 = *(const half8*)&Vs[buf][sub * 16 + l16][vch0];
      const half8 v23 = *(const half8*)&Vs[buf][sub * 16 + l16][vch1];
      const half4 va0 = {v01[0], v01[1], v01[2], v01[3]};
      const half4 va1 = {v01[4], v01[5], v01[6], v01[7]};
      const half4 va2 = {v23[0], v23[1], v23[2], v23[3]};
      const half4 va3 = {v23[4], v23[5], v23[6], v23[7]};
      o[sub] = mfma16k16(va0, p4[0], o[sub]);
      o[sub] = mfma16k16(va1, p4[1], o[sub]);
      o[sub] = mfma16k16(va2, p4[2], o[sub]);
      o[sub] = mfma16k16(va3, p4[3], o[sub]);
    }
    __builtin_amdgcn_s_setprio(0);

    __syncthreads();   // single barrier per iteration

    // prefetch tile kt+2 (consumed by the write in the next body)
    if (kt < 30) {
      const int k2 = (kt + 2) * 64;
      const int gk = (bh * SS + k2 + sr) * DHH + sc;
      pK = *(const half8*)(kh + gk);
      pL = *(const half8*)(kl + gk);
      pV = *(const half8*)(vt + (bh * DHH + sr) * SS + k2 + sc);
    }
  };

  #pragma unroll 1
  for (int kt = 0; kt < 32; kt += 2) {
    body(0, kt);
    body(1, kt + 1);
  }

  // epilogue: reduce per-lane psum across the q-column's 4 lane groups
  float lsum = l_lane;
  lsum += __shfl_xor(lsum, 16);
  lsum += __shfl_xor(lsum, 32);
  const float inv = 1.0f / lsum;
  const int s = qt * 128 + wid * 16 + l16;
  #pragma unroll
  for (int sub = 0; sub < 4; ++sub) {
    half4 ov;
    #pragma unroll
    for (int r = 0; r < 4; ++r) ov[r] = (_Float16)(o[sub][r] * inv);
    *(half4*)(agg + (b * SS + s) * (HH * DHH) + h * DHH + sub * 16 + q4 * 4) = ov;
  }
}

// ---------------------------------------------------------------------------
// Kernel 3: output projection (unchanged R17/R18 ring form).
// ---------------------------------------------------------------------------
__global__ __launch_bounds__(512) void out_gemm_kernel(
    const _Float16* __restrict__ agg, const _Float16* __restrict__ Wot,
    float* __restrict__ out)
{
  __shared__ alignas(16) _Float16 sbuf[4][2][128 * 32];   // 64 KB
  const int n0 = blockIdx.x * 128;
  const int m0 = blockIdx.y * 128;
  const int t = (int)threadIdx.x;
  const int lane = t & 63, wid = t >> 6;          // wid in [0,8)
  const int l16 = lane & 15, q4 = lane >> 4;
  const int mw = (wid & 3) * 32, nw = (wid >> 2) * 64;

  const int g  = (lane & 7) ^ ((lane >> 3) & 7);
  const int grow  = (lane >> 3) * 2 + (g >> 2);
  const int gcol8 = (g & 3) * 8;
  const int laneoff = (l16 >> 1) * 128 + (((((l16 & 1) << 2) | q4) ^ (l16 >> 1)) * 16);

  const int arr = wid & 1;
  const int rowq = (wid >> 1) * 32;
  const _Float16* src = (arr == 0) ? (agg + m0 * 1024) : (Wot + n0 * 1024);
  const _Float16* gsrc = src + (rowq + grow) * 1024 + gcol8;

  const floatx4 z4 = {0.0f, 0.0f, 0.0f, 0.0f};
  floatx4 acc[2][4];
  #pragma unroll
  for (int mi = 0; mi < 2; ++mi)
    #pragma unroll
    for (int ni = 0; ni < 4; ++ni) acc[mi][ni] = z4;

  auto stage = [&](int buf, int kt2) {
    const _Float16* gp = gsrc + kt2 * 32;
    _Float16* dst = &sbuf[buf][arr][rowq * 32];
    #pragma unroll
    for (int j = 0; j < 2; ++j)
      dma16(gp + j * 16 * 1024, dst + j * 16 * 32);
  };

  auto compute = [&](int buf) {
    const char* sA = (const char*)&sbuf[buf][0][0];
    const char* sB = (const char*)&sbuf[buf][1][0];
    half8 a_f[2];
    #pragma unroll
    for (int mi = 0; mi < 2; ++mi)
      a_f[mi] = *(const half8*)(sA + (mw + mi * 16) * 64 + laneoff);
    #pragma unroll
    for (int ni = 0; ni < 4; ++ni) {
      const half8 b_f = *(const half8*)(sB + (nw + ni * 16) * 64 + laneoff);
      #pragma unroll
      for (int mi = 0; mi < 2; ++mi)
        acc[mi][ni] = mfma16(a_f[mi], b_f, acc[mi][ni]);
    }
  };

  stage(0, 0);
  stage(1, 1);
  stage(2, 2);

#define OUT_PHASE(P, BUF, VC)                                  \
  asm volatile("s_waitcnt vmcnt(" #VC ")" ::: "memory");       \
  __builtin_amdgcn_s_barrier();                                \
  if ((P) + 3 < 32) stage(((P) + 3) & 3, (P) + 3);             \
  compute(BUF);

  #pragma unroll 1
  for (int p4 = 0; p4 < 28; p4 += 4) {
    OUT_PHASE(p4 + 0, 0, 4)
    OUT_PHASE(p4 + 1, 1, 4)
    OUT_PHASE(p4 + 2, 2, 4)
    OUT_PHASE(p4 + 3, 3, 4)
  }
  OUT_PHASE(28, 0, 4)
  OUT_PHASE(29, 1, 4)
  OUT_PHASE(30, 2, 2)
  OUT_PHASE(31, 3, 0)
#undef OUT_PHASE

  #pragma unroll
  for (int ni = 0; ni < 4; ++ni)
    #pragma unroll
    for (int mi = 0; mi < 2; ++mi)
      #pragma unroll
      for (int r = 0; r < 4; ++r)
        out[(m0 + mw + mi * 16 + q4 * 4 + r) * 1024 + n0 + nw + ni * 16 + l16] =
            acc[mi][ni][r];
}

// ---------------------------------------------------------------------------
extern "C" void kernel_launch(void* const* d_in, const int* in_sizes, int n_in,
                              void* d_out, int out_size, void* d_ws, size_t ws_size,
                              hipStream_t stream)
{
  const float* tokens = (const float*)d_in[0];
  const float* wq = (const float*)d_in[1];
  const float* wk = (const float*)d_in[2];
  const float* wv = (const float*)d_in[3];
  const float* wo = (const float*)d_in[4];
  float* out = (float*)d_out;

  char* ws = (char*)d_ws;
  // layout (bytes):
  //   qh 0          ql 8388608    kh 16777216   kl 25165824   vt 33554432
  //   Wh 41943040 (6291456)   Wl 48234496 (6291456)   Wot 54525952 (2097152)
  //   th 56623104 (8388608)   tl 65011712 (8388608)      total 73400320
  //   agg aliases th (th dead after qkv_gemm)
  _Float16* qh  = (_Float16*)(ws);
  _Float16* ql  = (_Float16*)(ws + 8388608);
  _Float16* kh  = (_Float16*)(ws + 16777216);
  _Float16* kl  = (_Float16*)(ws + 25165824);
  _Float16* vt  = (_Float16*)(ws + 33554432);
  _Float16* Wh  = (_Float16*)(ws + 41943040);
  _Float16* Wl  = (_Float16*)(ws + 48234496);
  _Float16* Wot = (_Float16*)(ws + 54525952);
  _Float16* th  = (_Float16*)(ws + 56623104);
  _Float16* tl  = (_Float16*)(ws + 65011712);
  _Float16* agg = (_Float16*)(ws + 56623104);

  convert_kernel<<<dim3(16, 16, 4), 256, 0, stream>>>(wq, wk, wv, wo, Wh, Wl, Wot);
  tokens_split_kernel<<<2048, 256, 0, stream>>>(tokens, th, tl);
  qkv_gemm_kernel<<<dim3(24, 32), 512, 0, stream>>>(th, tl, Wh, Wl, qh, ql, kh, kl, vt);
  attn_kernel<<<dim3(16, 16, 2), 512, 0, stream>>>(qh, ql, kh, kl, vt, agg);
  out_gemm_kernel<<<dim3(8, 32), 512, 0, stream>>>(agg, Wot, out);
}